// Round 4
// baseline (847.952 us; speedup 1.0000x reference)
//
#include <hip/hip_runtime.h>
#include <hip/hip_bf16.h>
#include <stdint.h>
#include <math.h>

typedef __attribute__((ext_vector_type(4))) float f32x4;
typedef __attribute__((ext_vector_type(8))) short s16x8;

typedef const __attribute__((address_space(1))) void* gas_ptr;
typedef __attribute__((address_space(3))) void* las_ptr;

__device__ __forceinline__ float bf2f(unsigned short u) {
    union { unsigned int i; float f; } x; x.i = ((unsigned int)u) << 16; return x.f;
}
__device__ __forceinline__ unsigned short f2bf(float f) {
    union { float f; unsigned int u; } x; x.f = f;
    unsigned int r = x.u + 0x7FFFu + ((x.u >> 16) & 1u);
    return (unsigned short)(r >> 16);
}

// ---------------- fp32 -> bf16 ----------------
__global__ __launch_bounds__(256) void cvt_f32_bf16(const float* __restrict__ src,
                                                    unsigned short* __restrict__ dst,
                                                    long n) {
    long i = ((long)blockIdx.x * 256 + threadIdx.x) * 8;
    if (i + 8 > n) return;
    f32x4 a = *(const f32x4*)(src + i);
    f32x4 b = *(const f32x4*)(src + i + 4);
    s16x8 o;
    o[0] = (short)f2bf(a[0]); o[1] = (short)f2bf(a[1]);
    o[2] = (short)f2bf(a[2]); o[3] = (short)f2bf(a[3]);
    o[4] = (short)f2bf(b[0]); o[5] = (short)f2bf(b[1]);
    o[6] = (short)f2bf(b[2]); o[7] = (short)f2bf(b[3]);
    *(s16x8*)(dst + i) = o;
}

// ============ 256x256 8-phase bf16 GEMM: C = alpha * A[M,K] @ B[N,K]^T ============
// Phase-PIPELINED variant: fragment ds_reads are issued one phase ahead of their
// consuming MFMA; pre-MFMA waits are COUNTED lgkmcnt (leave the new reads in
// flight) so the LDS pipe drains under the MFMA clusters instead of serializing.
//   P0: read B1 (4)   -> used P1   | stage t+1.A1 | lgkm(4)  | MFMA(0,0) afA,bq0
//   P1: read A1 (8)   -> used P2   | stage t+1.B1 | lgkm(8)  | MFMA(0,1) afA,bq1 | vmcnt(4)
//   P2: read t+1.A0(8)-> used t+1  | stage t+2.A0 | lgkm(8)  | MFMA(1,1) afB,bq1
//   P3: (post-MFMA) read t+1.B0(4) | stage t+2.B0 |          | MFMA(1,0) afB,bq0 | vmcnt(4)
// vmcnt(4) before closing barriers gates cross-wave glds visibility; never
// drains below 4 in flight (T4). Swizzle (T2) as before. kt unrolled x2 so the
// LDS buffer parity is compile-time. Requires nt even and >= 4.
template <typename CT>
__global__ __launch_bounds__(512, 2)
void gemm256_bt(const unsigned short* __restrict__ A,
                const unsigned short* __restrict__ B,
                CT* __restrict__ C,
                int N, int K, int nt,
                long sA, long sB, long sC, float alpha)
{
    A += (long)blockIdx.z * sA;
    B += (long)blockIdx.z * sB;
    C += (long)blockIdx.z * sC;

    __shared__ unsigned short L[2][2][2][128][64];   // 128 KiB

    const int t    = threadIdx.x;
    const int lane = t & 63;
    const int wid  = t >> 6;        // 0..7
    const int wm   = wid >> 2;      // 0..1
    const int wn   = wid & 3;       // 0..3
    const long brow = (long)blockIdx.x * 256;
    const long bcol = (long)blockIdx.y * 256;

    const int lr = lane & 15;
    const int hi = lane >> 4;            // 0..3
    const int sw = (lr & 7) << 3;        // ds_read swizzle (element units)

    // ---- staging precompute: thread t, chunk j handles linear u = t + 512j ----
    int voff[2];                      // LDS element offset u*8
    const unsigned short* pA[2][2];   // [sub][j] global src (pre-swizzled), k0=0
    const unsigned short* pB[2][2];
    {
        const unsigned short* Ab = A + brow * K;
        const unsigned short* Bb = B + bcol * K;
        #pragma unroll
        for (int j = 0; j < 2; ++j) {
            int u  = t + 512 * j;
            int ix = u >> 3;                       // phys row in [128][64] region
            int cg = u & 7;
            int cs = (cg * 8) ^ ((ix & 7) << 3);   // pre-swizzled col
            voff[j] = u * 8;
            long ra0 = ((long)(ix >> 6) << 7) | (0 << 6) | (ix & 63);
            long ra1 = ((long)(ix >> 6) << 7) | (1 << 6) | (ix & 63);
            long rb0 = ((long)(ix >> 5) << 6) | (0 << 5) | (ix & 31);
            long rb1 = ((long)(ix >> 5) << 6) | (1 << 5) | (ix & 31);
            pA[0][j] = Ab + ra0 * K + cs;
            pA[1][j] = Ab + ra1 * K + cs;
            pB[0][j] = Bb + rb0 * K + cs;
            pB[1][j] = Bb + rb1 * K + cs;
        }
    }

#define STAGE_A(H, KT, BUF) do { \
    _Pragma("unroll") \
    for (int j = 0; j < 2; ++j) \
        __builtin_amdgcn_global_load_lds((gas_ptr)(pA[H][j] + (long)(KT) * 64), \
            (las_ptr)(&L[BUF][0][H][0][0] + voff[j]), 16, 0, 0); \
} while (0)
#define STAGE_B(H, KT, BUF) do { \
    _Pragma("unroll") \
    for (int j = 0; j < 2; ++j) \
        __builtin_amdgcn_global_load_lds((gas_ptr)(pB[H][j] + (long)(KT) * 64), \
            (las_ptr)(&L[BUF][1][H][0][0] + voff[j]), 16, 0, 0); \
} while (0)

#define LOAD_A(DST, BUF, SUB) do { \
    _Pragma("unroll") \
    for (int m = 0; m < 4; ++m) \
        _Pragma("unroll") \
        for (int kk = 0; kk < 2; ++kk) \
            DST[m][kk] = *(const s16x8*)&L[BUF][0][SUB][wm * 64 + m * 16 + lr][(kk * 32 + hi * 8) ^ sw]; \
} while (0)
#define LOAD_B(DST, BUF, SUB) do { \
    _Pragma("unroll") \
    for (int n = 0; n < 2; ++n) \
        _Pragma("unroll") \
        for (int kk = 0; kk < 2; ++kk) \
            DST[n][kk] = *(const s16x8*)&L[BUF][1][SUB][wn * 32 + n * 16 + lr][(kk * 32 + hi * 8) ^ sw]; \
} while (0)
#define MFMA_Q(QM, QN, AF, BQ) do { \
    __builtin_amdgcn_s_setprio(1); \
    _Pragma("unroll") \
    for (int m = 0; m < 4; ++m) \
        _Pragma("unroll") \
        for (int n = 0; n < 2; ++n) \
            _Pragma("unroll") \
            for (int kk = 0; kk < 2; ++kk) \
                acc[(QM) * 4 + m][(QN) * 2 + n] = __builtin_amdgcn_mfma_f32_16x16x32_bf16( \
                    AF[m][kk], BQ[n][kk], acc[(QM) * 4 + m][(QN) * 2 + n], 0, 0, 0); \
    __builtin_amdgcn_s_setprio(0); \
} while (0)

    f32x4 acc[8][4];
    #pragma unroll
    for (int m = 0; m < 8; ++m)
        #pragma unroll
        for (int n = 0; n < 4; ++n)
            acc[m][n] = {0.f, 0.f, 0.f, 0.f};

    s16x8 afA[4][2], afB[4][2], bq0[2][2], bq1[2][2];

    // ---- prologue (requires nt >= 2): stage t0 fully + t1.A0,B0 ----
    STAGE_A(0, 0, 0); STAGE_B(0, 0, 0); STAGE_A(1, 0, 0); STAGE_B(1, 0, 0);
    STAGE_A(0, 1, 1); STAGE_B(0, 1, 1);
    asm volatile("s_waitcnt vmcnt(8)" ::: "memory");   // t0.A0,B0 landed
    __builtin_amdgcn_s_barrier();
    LOAD_A(afA, 0, 0);
    LOAD_B(bq0, 0, 0);
    asm volatile("s_waitcnt vmcnt(4)" ::: "memory");   // t0.A1,B1 landed
    __builtin_amdgcn_s_barrier();

#define TILE(CUR, KTE) do { \
    const int kt_ = (KTE); \
    /* ---- P0 ---- */ \
    LOAD_B(bq1, CUR, 1); \
    if (kt_ + 1 < nt) STAGE_A(1, kt_ + 1, CUR ^ 1); \
    __builtin_amdgcn_s_barrier(); \
    asm volatile("s_waitcnt lgkmcnt(4)" ::: "memory"); \
    __builtin_amdgcn_sched_barrier(0); \
    MFMA_Q(0, 0, afA, bq0); \
    __builtin_amdgcn_s_barrier(); \
    /* ---- P1 ---- */ \
    LOAD_A(afB, CUR, 1); \
    if (kt_ + 1 < nt) STAGE_B(1, kt_ + 1, CUR ^ 1); \
    __builtin_amdgcn_s_barrier(); \
    asm volatile("s_waitcnt lgkmcnt(8)" ::: "memory"); \
    __builtin_amdgcn_sched_barrier(0); \
    MFMA_Q(0, 1, afA, bq1); \
    asm volatile("s_waitcnt vmcnt(4)" ::: "memory"); \
    __builtin_amdgcn_s_barrier(); \
    /* ---- P2 ---- */ \
    if (kt_ + 1 < nt) { \
        LOAD_A(afA, CUR ^ 1, 0); \
        if (kt_ + 2 < nt) STAGE_A(0, kt_ + 2, CUR); \
    } \
    __builtin_amdgcn_s_barrier(); \
    if (kt_ + 1 < nt) { asm volatile("s_waitcnt lgkmcnt(8)" ::: "memory"); } \
    else              { asm volatile("s_waitcnt lgkmcnt(0)" ::: "memory"); } \
    __builtin_amdgcn_sched_barrier(0); \
    MFMA_Q(1, 1, afB, bq1); \
    __builtin_amdgcn_s_barrier(); \
    /* ---- P3 ---- */ \
    if (kt_ + 2 < nt) STAGE_B(0, kt_ + 2, CUR); \
    __builtin_amdgcn_s_barrier(); \
    MFMA_Q(1, 0, afB, bq0); \
    if (kt_ + 1 < nt) LOAD_B(bq0, CUR ^ 1, 0); \
    asm volatile("s_waitcnt vmcnt(4)" ::: "memory"); \
    __builtin_amdgcn_s_barrier(); \
} while (0)

    for (int kt = 0; kt < nt; kt += 2) {
        TILE(0, kt);
        TILE(1, kt + 1);
    }
#undef TILE
#undef STAGE_A
#undef STAGE_B
#undef LOAD_A
#undef LOAD_B
#undef MFMA_Q

    // ---- epilogue: C[row][col], row = 16*am + hi*4 + i, col = 16*an + lr ----
    #pragma unroll
    for (int m = 0; m < 8; ++m) {
        #pragma unroll
        for (int n = 0; n < 4; ++n) {
            #pragma unroll
            for (int i = 0; i < 4; ++i) {
                long row = brow + wm * 128 + m * 16 + hi * 4 + i;
                long col = bcol + wn * 64 + n * 16 + lr;
                float vv = acc[m][n][i] * alpha;
                if constexpr (sizeof(CT) == 2) {
                    ((unsigned short*)C)[row * (long)N + col] = f2bf(vv);
                } else {
                    ((float*)C)[row * (long)N + col] = vv;
                }
            }
        }
    }
}

// ---------------- bf16 transpose: dst[c][r] = src[r][c], per-batch ----------------
__global__ __launch_bounds__(256) void transpose_bf16(const unsigned short* __restrict__ src,
                                                      unsigned short* __restrict__ dst,
                                                      int srows, int scols) {
    __shared__ unsigned short tile[64][66];
    const long bofs = (long)blockIdx.z * srows * scols;
    const unsigned short* s = src + bofs;
    unsigned short* d = dst + bofs;
    const int c0 = blockIdx.x * 64;
    const int r0 = blockIdx.y * 64;
    const int tx = threadIdx.x & 15;
    const int ty = threadIdx.x >> 4;

    #pragma unroll
    for (int k = 0; k < 4; ++k) {
        int r = ty + 16 * k;
        ushort4 v = *(const ushort4*)(s + (long)(r0 + r) * scols + c0 + tx * 4);
        tile[r][tx * 4 + 0] = v.x; tile[r][tx * 4 + 1] = v.y;
        tile[r][tx * 4 + 2] = v.z; tile[r][tx * 4 + 3] = v.w;
    }
    __syncthreads();
    #pragma unroll
    for (int k = 0; k < 4; ++k) {
        int dr = ty + 16 * k;
        ushort4 v;
        v.x = tile[tx * 4 + 0][dr]; v.y = tile[tx * 4 + 1][dr];
        v.z = tile[tx * 4 + 2][dr]; v.w = tile[tx * 4 + 3][dr];
        *(ushort4*)(d + (long)(c0 + dr) * srows + r0 + tx * 4) = v;
    }
}

// ---------------- row softmax, in place, bf16, ncols = 4096 ----------------
__global__ __launch_bounds__(256) void softmax_inplace(unsigned short* __restrict__ S, int ncols) {
    const long row = blockIdx.x;
    unsigned short* p = S + row * (long)ncols;
    const int t = threadIdx.x;
    const int wid = t >> 6;

    ushort4 raw[4];
    const ushort4* pv = (const ushort4*)(p + t * 16);
    #pragma unroll
    for (int i = 0; i < 4; ++i) raw[i] = pv[i];

    float v[16];
    float mx = -1e30f;
    #pragma unroll
    for (int i = 0; i < 4; ++i) {
        v[4*i+0] = bf2f(raw[i].x); v[4*i+1] = bf2f(raw[i].y);
        v[4*i+2] = bf2f(raw[i].z); v[4*i+3] = bf2f(raw[i].w);
    }
    #pragma unroll
    for (int i = 0; i < 16; ++i) mx = fmaxf(mx, v[i]);
    #pragma unroll
    for (int off = 32; off > 0; off >>= 1) mx = fmaxf(mx, __shfl_xor(mx, off));

    __shared__ float red[8];
    if ((t & 63) == 0) red[wid] = mx;
    __syncthreads();
    mx = fmaxf(fmaxf(red[0], red[1]), fmaxf(red[2], red[3]));

    float sum = 0.f;
    #pragma unroll
    for (int i = 0; i < 16; ++i) { v[i] = __expf(v[i] - mx); sum += v[i]; }
    #pragma unroll
    for (int off = 32; off > 0; off >>= 1) sum += __shfl_xor(sum, off);
    __syncthreads();
    if ((t & 63) == 0) red[4 + wid] = sum;
    __syncthreads();
    sum = red[4] + red[5] + red[6] + red[7];
    const float inv = 1.0f / sum;

    ushort4* po = (ushort4*)(p + t * 16);
    #pragma unroll
    for (int i = 0; i < 4; ++i) {
        ushort4 o;
        o.x = f2bf(v[4*i+0] * inv); o.y = f2bf(v[4*i+1] * inv);
        o.z = f2bf(v[4*i+2] * inv); o.w = f2bf(v[4*i+3] * inv);
        po[i] = o;
    }
}

extern "C" void kernel_launch(void* const* d_in, const int* in_sizes, int n_in,
                              void* d_out, int out_size, void* d_ws, size_t ws_size,
                              hipStream_t stream) {
    const float* x  = (const float*)d_in[0];
    const float* wq = (const float*)d_in[1];
    const float* wk = (const float*)d_in[2];
    const float* wv = (const float*)d_in[3];
    const float* wo = (const float*)d_in[4];
    float* out = (float*)d_out;

    const long SDIM = 2048, SEQ = 4096, BATCH = 2;
    const long MS = BATCH * SEQ;       // 8192
    const long XN = MS * SDIM;         // 16,777,216
    const long WN = SDIM * SDIM;       // 4,194,304

    unsigned short* ws  = (unsigned short*)d_ws;
    unsigned short* Xbf = ws;               // XN elems (reused as Vt later)
    unsigned short* Wqb = ws + XN;
    unsigned short* Wkb = Wqb + WN;
    unsigned short* Wvb = Wkb + WN;
    unsigned short* Wob = Wvb + WN;
    unsigned short* Qb  = Wob + WN;         // XN (reused as Ctx later)
    unsigned short* Kb  = Qb + XN;
    unsigned short* Vb  = Kb + XN;
    unsigned short* Sb  = Vb + XN;          // 2*4096*4096 bf16
    unsigned short* Vt  = Xbf;
    unsigned short* Ctx = Qb;

    // fp32 -> bf16 conversions
    cvt_f32_bf16<<<(int)(XN / 2048), 256, 0, stream>>>(x,  Xbf, XN);
    cvt_f32_bf16<<<(int)(WN / 2048), 256, 0, stream>>>(wq, Wqb, WN);
    cvt_f32_bf16<<<(int)(WN / 2048), 256, 0, stream>>>(wk, Wkb, WN);
    cvt_f32_bf16<<<(int)(WN / 2048), 256, 0, stream>>>(wv, Wvb, WN);
    cvt_f32_bf16<<<(int)(WN / 2048), 256, 0, stream>>>(wo, Wob, WN);

    // projections: [8192,2048] = Xbf @ W^T
    dim3 gp((unsigned)(MS / 256), (unsigned)(SDIM / 256), 1);
    gemm256_bt<unsigned short><<<gp, 512, 0, stream>>>(Xbf, Wqb, Qb, (int)SDIM, (int)SDIM, (int)(SDIM / 64), 0, 0, 0, 1.0f);
    gemm256_bt<unsigned short><<<gp, 512, 0, stream>>>(Xbf, Wkb, Kb, (int)SDIM, (int)SDIM, (int)(SDIM / 64), 0, 0, 0, 1.0f);
    gemm256_bt<unsigned short><<<gp, 512, 0, stream>>>(Xbf, Wvb, Vb, (int)SDIM, (int)SDIM, (int)(SDIM / 64), 0, 0, 0, 1.0f);

    // V -> V^T per batch (Vt overwrites Xbf region; X no longer needed)
    dim3 gt((unsigned)(SDIM / 64), (unsigned)(SEQ / 64), (unsigned)BATCH);
    transpose_bf16<<<gt, 256, 0, stream>>>(Vb, Vt, (int)SEQ, (int)SDIM);

    // scores: S[b] = Q[b] @ K[b]^T * (1/sqrt(D))
    const float scale = 1.0f / sqrtf((float)SDIM);
    dim3 gs((unsigned)(SEQ / 256), (unsigned)(SEQ / 256), (unsigned)BATCH);
    gemm256_bt<unsigned short><<<gs, 512, 0, stream>>>(Qb, Kb, Sb, (int)SEQ, (int)SDIM, (int)(SDIM / 64),
                                                       SEQ * SDIM, SEQ * SDIM, SEQ * SEQ, scale);

    // softmax rows in place
    softmax_inplace<<<(int)(BATCH * SEQ), 256, 0, stream>>>(Sb, (int)SEQ);

    // ctx[b] = P[b] @ Vt[b]^T : M=SEQ, N=SDIM, K=SEQ  (Ctx overwrites Qb)
    dim3 gc((unsigned)(SEQ / 256), (unsigned)(SDIM / 256), (unsigned)BATCH);
    gemm256_bt<unsigned short><<<gc, 512, 0, stream>>>(Sb, Vt, Ctx, (int)SDIM, (int)SEQ, (int)(SEQ / 64),
                                                       SEQ * SEQ, SDIM * SEQ, SEQ * SDIM, 1.0f);

    // out = Ctx @ Wo^T  (fp32 out, flat [8192,2048])
    gemm256_bt<float><<<gp, 512, 0, stream>>>(Ctx, Wob, out, (int)SDIM, (int)SDIM, (int)(SDIM / 64), 0, 0, 0, 1.0f);
}

// Round 5
// 599.427 us; speedup vs baseline: 1.4146x; 1.4146x over previous
//
#include <hip/hip_runtime.h>
#include <hip/hip_bf16.h>
#include <stdint.h>
#include <math.h>

typedef __attribute__((ext_vector_type(4))) float f32x4;
typedef __attribute__((ext_vector_type(8))) short s16x8;

typedef const __attribute__((address_space(1))) void* gas_ptr;
typedef __attribute__((address_space(3))) void* las_ptr;

__device__ __forceinline__ float bf2f(unsigned short u) {
    union { unsigned int i; float f; } x; x.i = ((unsigned int)u) << 16; return x.f;
}
__device__ __forceinline__ unsigned short f2bf(float f) {
    union { float f; unsigned int u; } x; x.f = f;
    unsigned int r = x.u + 0x7FFFu + ((x.u >> 16) & 1u);
    return (unsigned short)(r >> 16);
}

// ---------------- fp32 -> bf16 ----------------
__global__ __launch_bounds__(256) void cvt_f32_bf16(const float* __restrict__ src,
                                                    unsigned short* __restrict__ dst,
                                                    long n) {
    long i = ((long)blockIdx.x * 256 + threadIdx.x) * 8;
    if (i + 8 > n) return;
    f32x4 a = *(const f32x4*)(src + i);
    f32x4 b = *(const f32x4*)(src + i + 4);
    s16x8 o;
    o[0] = (short)f2bf(a[0]); o[1] = (short)f2bf(a[1]);
    o[2] = (short)f2bf(a[2]); o[3] = (short)f2bf(a[3]);
    o[4] = (short)f2bf(b[0]); o[5] = (short)f2bf(b[1]);
    o[6] = (short)f2bf(b[2]); o[7] = (short)f2bf(b[3]);
    *(s16x8*)(dst + i) = o;
}

// ============ 256x256 8-phase bf16 GEMM: C = alpha * A[M,K] @ B[N,K]^T ============
// Round-3 structure (same-phase read->lgkm(0)->MFMA, 2 barriers/phase) with
// DEEP staging: all half-tiles for tile t+2 are staged during tile t
// (P1: A0+B0, P2: B1, P3: A1), so every half-tile lands 5-7 phases (~2000 cyc)
// before its consuming ds_read -- the r3 boundary stall (A0/B0 staged only 1-2
// phases = ~400-800 cyc < HBM latency ~900 cyc before use) is removed.
// Counted vmcnt (T4, never 0 in steady state): P0-end vmcnt(10) lands B1(t),
// P1-end vmcnt(12) lands A1(t), boundary vmcnt(12) lands A0,B0(t+1).
// Steady-state glds queue: 12 ->P0 10 ->P1 +4,14->12 ->P2 +2,14 ->P3 +2,16
// ->boundary 12 (periodic). Epilogue: kt=nt-2 uses vmcnt(8)@P1-end and
// vmcnt(0)@boundary (full drain once, 1 of nt tiles).
// Swizzle (T2): element col ^= ((row&7)<<3); pre-swizzled global source for
// the linear global_load_lds dest + same XOR on ds_read address (rule 21).
template <typename CT>
__global__ __launch_bounds__(512, 2)
void gemm256_bt(const unsigned short* __restrict__ A,
                const unsigned short* __restrict__ B,
                CT* __restrict__ C,
                int N, int K, int nt,
                long sA, long sB, long sC, float alpha)
{
    A += (long)blockIdx.z * sA;
    B += (long)blockIdx.z * sB;
    C += (long)blockIdx.z * sC;

    __shared__ unsigned short L[2][2][2][128][64];   // 128 KiB

    const int t    = threadIdx.x;
    const int lane = t & 63;
    const int wid  = t >> 6;        // 0..7
    const int wm   = wid >> 2;      // 0..1
    const int wn   = wid & 3;       // 0..3
    const long brow = (long)blockIdx.x * 256;
    const long bcol = (long)blockIdx.y * 256;

    const int lr = lane & 15;
    const int hi = lane >> 4;            // 0..3
    const int sw = (lr & 7) << 3;        // ds_read swizzle (element units)

    // ---- staging precompute: thread t, chunk j handles linear u = t + 512j ----
    int voff[2];                      // LDS element offset u*8
    const unsigned short* pA[2][2];   // [sub][j] global src (pre-swizzled), k0=0
    const unsigned short* pB[2][2];
    {
        const unsigned short* Ab = A + brow * K;
        const unsigned short* Bb = B + bcol * K;
        #pragma unroll
        for (int j = 0; j < 2; ++j) {
            int u  = t + 512 * j;
            int ix = u >> 3;                       // phys row in [128][64] region
            int cg = u & 7;
            int cs = (cg * 8) ^ ((ix & 7) << 3);   // pre-swizzled col
            voff[j] = u * 8;
            long ra0 = ((long)(ix >> 6) << 7) | (0 << 6) | (ix & 63);
            long ra1 = ((long)(ix >> 6) << 7) | (1 << 6) | (ix & 63);
            long rb0 = ((long)(ix >> 5) << 6) | (0 << 5) | (ix & 31);
            long rb1 = ((long)(ix >> 5) << 6) | (1 << 5) | (ix & 31);
            pA[0][j] = Ab + ra0 * K + cs;
            pA[1][j] = Ab + ra1 * K + cs;
            pB[0][j] = Bb + rb0 * K + cs;
            pB[1][j] = Bb + rb1 * K + cs;
        }
    }

#define STAGE_A(H, KT) do { \
    _Pragma("unroll") \
    for (int j = 0; j < 2; ++j) \
        __builtin_amdgcn_global_load_lds((gas_ptr)(pA[H][j] + (long)(KT) * 64), \
            (las_ptr)(&L[(KT) & 1][0][H][0][0] + voff[j]), 16, 0, 0); \
} while (0)
#define STAGE_B(H, KT) do { \
    _Pragma("unroll") \
    for (int j = 0; j < 2; ++j) \
        __builtin_amdgcn_global_load_lds((gas_ptr)(pB[H][j] + (long)(KT) * 64), \
            (las_ptr)(&L[(KT) & 1][1][H][0][0] + voff[j]), 16, 0, 0); \
} while (0)

#define LOAD_AF(QM) do { \
    _Pragma("unroll") \
    for (int m = 0; m < 4; ++m) \
        _Pragma("unroll") \
        for (int kk = 0; kk < 2; ++kk) \
            af[m][kk] = *(const s16x8*)&L[cur][0][QM][wm * 64 + m * 16 + lr][(kk * 32 + hi * 8) ^ sw]; \
} while (0)
#define LOAD_BQ(DST, QN) do { \
    _Pragma("unroll") \
    for (int n = 0; n < 2; ++n) \
        _Pragma("unroll") \
        for (int kk = 0; kk < 2; ++kk) \
            DST[n][kk] = *(const s16x8*)&L[cur][1][QN][wn * 32 + n * 16 + lr][(kk * 32 + hi * 8) ^ sw]; \
} while (0)
#define MFMA_Q(QM, QN, BQ) do { \
    __builtin_amdgcn_s_setprio(1); \
    _Pragma("unroll") \
    for (int m = 0; m < 4; ++m) \
        _Pragma("unroll") \
        for (int n = 0; n < 2; ++n) \
            _Pragma("unroll") \
            for (int kk = 0; kk < 2; ++kk) \
                acc[(QM) * 4 + m][(QN) * 2 + n] = __builtin_amdgcn_mfma_f32_16x16x32_bf16( \
                    af[m][kk], BQ[n][kk], acc[(QM) * 4 + m][(QN) * 2 + n], 0, 0, 0); \
    __builtin_amdgcn_s_setprio(0); \
} while (0)

    f32x4 acc[8][4];
    #pragma unroll
    for (int m = 0; m < 8; ++m)
        #pragma unroll
        for (int n = 0; n < 4; ++n)
            acc[m][n] = {0.f, 0.f, 0.f, 0.f};

    // ---- prologue: stage tiles 0 and 1 in steady-state queue order ----
    // queue: [A0B0(0)4, B1(0)2, A1(0)2, A0B0(1)4, B1(1)2, A1(1)2] = 16
    STAGE_A(0, 0); STAGE_B(0, 0); STAGE_B(1, 0); STAGE_A(1, 0);
    STAGE_A(0, 1); STAGE_B(0, 1); STAGE_B(1, 1); STAGE_A(1, 1);
    asm volatile("s_waitcnt vmcnt(12)" ::: "memory");   // A0,B0(0) landed
    __builtin_amdgcn_s_barrier();

    for (int kt = 0; kt < nt; ++kt) {
        const int cur = kt & 1;
        s16x8 af[4][2], bq0[2][2], bq1[2][2];

        // ---- P0: read A0 + B0 (12); no staging; MFMA (0,0) ----
        LOAD_AF(0);
        LOAD_BQ(bq0, 0);
        asm volatile("s_waitcnt lgkmcnt(8)" ::: "memory");
        __builtin_amdgcn_s_barrier();
        asm volatile("s_waitcnt lgkmcnt(0)" ::: "memory");
        MFMA_Q(0, 0, bq0);
        asm volatile("s_waitcnt vmcnt(10)" ::: "memory");   // B1(t) landed
        __builtin_amdgcn_s_barrier();

        // ---- P1: read B1 (4), stage A0+B0(t+2), MFMA (0,1) [af reused] ----
        LOAD_BQ(bq1, 1);
        if (kt + 2 < nt) { STAGE_A(0, kt + 2); STAGE_B(0, kt + 2); }
        __builtin_amdgcn_s_barrier();
        asm volatile("s_waitcnt lgkmcnt(0)" ::: "memory");
        MFMA_Q(0, 1, bq1);
        if (kt + 2 < nt) asm volatile("s_waitcnt vmcnt(12)" ::: "memory");  // A1(t) landed
        else             asm volatile("s_waitcnt vmcnt(8)"  ::: "memory");
        __builtin_amdgcn_s_barrier();

        // ---- P2: read A1 (8), stage B1(t+2), MFMA (1,1) [bq1 reused] ----
        LOAD_AF(1);
        if (kt + 2 < nt) STAGE_B(1, kt + 2);
        asm volatile("s_waitcnt lgkmcnt(4)" ::: "memory");
        __builtin_amdgcn_s_barrier();
        asm volatile("s_waitcnt lgkmcnt(0)" ::: "memory");
        MFMA_Q(1, 1, bq1);
        __builtin_amdgcn_s_barrier();

        // ---- P3: stage A1(t+2), MFMA (1,0) [af + bq0 reused] ----
        if (kt + 2 < nt) STAGE_A(1, kt + 2);
        __builtin_amdgcn_s_barrier();
        MFMA_Q(1, 0, bq0);

        // tile boundary: A0,B0(t+1) landed; keep deep-prefetched loads in flight
        if (kt + 1 < nt) {
            if (kt + 2 < nt) asm volatile("s_waitcnt vmcnt(12)" ::: "memory");
            else             asm volatile("s_waitcnt vmcnt(0)"  ::: "memory");
            __builtin_amdgcn_s_barrier();
        }
    }
#undef STAGE_A
#undef STAGE_B
#undef LOAD_AF
#undef LOAD_BQ
#undef MFMA_Q

    // ---- epilogue: C[row][col], row = 16*am + hi*4 + i, col = 16*an + lr ----
    #pragma unroll
    for (int m = 0; m < 8; ++m) {
        #pragma unroll
        for (int n = 0; n < 4; ++n) {
            #pragma unroll
            for (int i = 0; i < 4; ++i) {
                long row = brow + wm * 128 + m * 16 + hi * 4 + i;
                long col = bcol + wn * 64 + n * 16 + lr;
                float vv = acc[m][n][i] * alpha;
                if constexpr (sizeof(CT) == 2) {
                    ((unsigned short*)C)[row * (long)N + col] = f2bf(vv);
                } else {
                    ((float*)C)[row * (long)N + col] = vv;
                }
            }
        }
    }
}

// ---------------- bf16 transpose: dst[c][r] = src[r][c], per-batch ----------------
__global__ __launch_bounds__(256) void transpose_bf16(const unsigned short* __restrict__ src,
                                                      unsigned short* __restrict__ dst,
                                                      int srows, int scols) {
    __shared__ unsigned short tile[64][66];
    const long bofs = (long)blockIdx.z * srows * scols;
    const unsigned short* s = src + bofs;
    unsigned short* d = dst + bofs;
    const int c0 = blockIdx.x * 64;
    const int r0 = blockIdx.y * 64;
    const int tx = threadIdx.x & 15;
    const int ty = threadIdx.x >> 4;

    #pragma unroll
    for (int k = 0; k < 4; ++k) {
        int r = ty + 16 * k;
        ushort4 v = *(const ushort4*)(s + (long)(r0 + r) * scols + c0 + tx * 4);
        tile[r][tx * 4 + 0] = v.x; tile[r][tx * 4 + 1] = v.y;
        tile[r][tx * 4 + 2] = v.z; tile[r][tx * 4 + 3] = v.w;
    }
    __syncthreads();
    #pragma unroll
    for (int k = 0; k < 4; ++k) {
        int dr = ty + 16 * k;
        ushort4 v;
        v.x = tile[tx * 4 + 0][dr]; v.y = tile[tx * 4 + 1][dr];
        v.z = tile[tx * 4 + 2][dr]; v.w = tile[tx * 4 + 3][dr];
        *(ushort4*)(d + (long)(c0 + dr) * srows + r0 + tx * 4) = v;
    }
}

// ---------------- row softmax, in place, bf16, ncols = 4096 ----------------
__global__ __launch_bounds__(256) void softmax_inplace(unsigned short* __restrict__ S, int ncols) {
    const long row = blockIdx.x;
    unsigned short* p = S + row * (long)ncols;
    const int t = threadIdx.x;
    const int wid = t >> 6;

    ushort4 raw[4];
    const ushort4* pv = (const ushort4*)(p + t * 16);
    #pragma unroll
    for (int i = 0; i < 4; ++i) raw[i] = pv[i];

    float v[16];
    float mx = -1e30f;
    #pragma unroll
    for (int i = 0; i < 4; ++i) {
        v[4*i+0] = bf2f(raw[i].x); v[4*i+1] = bf2f(raw[i].y);
        v[4*i+2] = bf2f(raw[i].z); v[4*i+3] = bf2f(raw[i].w);
    }
    #pragma unroll
    for (int i = 0; i < 16; ++i) mx = fmaxf(mx, v[i]);
    #pragma unroll
    for (int off = 32; off > 0; off >>= 1) mx = fmaxf(mx, __shfl_xor(mx, off));

    __shared__ float red[8];
    if ((t & 63) == 0) red[wid] = mx;
    __syncthreads();
    mx = fmaxf(fmaxf(red[0], red[1]), fmaxf(red[2], red[3]));

    float sum = 0.f;
    #pragma unroll
    for (int i = 0; i < 16; ++i) { v[i] = __expf(v[i] - mx); sum += v[i]; }
    #pragma unroll
    for (int off = 32; off > 0; off >>= 1) sum += __shfl_xor(sum, off);
    __syncthreads();
    if ((t & 63) == 0) red[4 + wid] = sum;
    __syncthreads();
    sum = red[4] + red[5] + red[6] + red[7];
    const float inv = 1.0f / sum;

    ushort4* po = (ushort4*)(p + t * 16);
    #pragma unroll
    for (int i = 0; i < 4; ++i) {
        ushort4 o;
        o.x = f2bf(v[4*i+0] * inv); o.y = f2bf(v[4*i+1] * inv);
        o.z = f2bf(v[4*i+2] * inv); o.w = f2bf(v[4*i+3] * inv);
        po[i] = o;
    }
}

extern "C" void kernel_launch(void* const* d_in, const int* in_sizes, int n_in,
                              void* d_out, int out_size, void* d_ws, size_t ws_size,
                              hipStream_t stream) {
    const float* x  = (const float*)d_in[0];
    const float* wq = (const float*)d_in[1];
    const float* wk = (const float*)d_in[2];
    const float* wv = (const float*)d_in[3];
    const float* wo = (const float*)d_in[4];
    float* out = (float*)d_out;

    const long SDIM = 2048, SEQ = 4096, BATCH = 2;
    const long MS = BATCH * SEQ;       // 8192
    const long XN = MS * SDIM;         // 16,777,216
    const long WN = SDIM * SDIM;       // 4,194,304

    unsigned short* ws  = (unsigned short*)d_ws;
    unsigned short* Xbf = ws;               // XN elems (reused as Vt later)
    unsigned short* Wqb = ws + XN;
    unsigned short* Wkb = Wqb + WN;
    unsigned short* Wvb = Wkb + WN;
    unsigned short* Wob = Wvb + WN;
    unsigned short* Qb  = Wob + WN;         // XN (reused as Ctx later)
    unsigned short* Kb  = Qb + XN;
    unsigned short* Vb  = Kb + XN;
    unsigned short* Sb  = Vb + XN;          // 2*4096*4096 bf16
    unsigned short* Vt  = Xbf;
    unsigned short* Ctx = Qb;

    // fp32 -> bf16 conversions
    cvt_f32_bf16<<<(int)(XN / 2048), 256, 0, stream>>>(x,  Xbf, XN);
    cvt_f32_bf16<<<(int)(WN / 2048), 256, 0, stream>>>(wq, Wqb, WN);
    cvt_f32_bf16<<<(int)(WN / 2048), 256, 0, stream>>>(wk, Wkb, WN);
    cvt_f32_bf16<<<(int)(WN / 2048), 256, 0, stream>>>(wv, Wvb, WN);
    cvt_f32_bf16<<<(int)(WN / 2048), 256, 0, stream>>>(wo, Wob, WN);

    // projections: [8192,2048] = Xbf @ W^T
    dim3 gp((unsigned)(MS / 256), (unsigned)(SDIM / 256), 1);
    gemm256_bt<unsigned short><<<gp, 512, 0, stream>>>(Xbf, Wqb, Qb, (int)SDIM, (int)SDIM, (int)(SDIM / 64), 0, 0, 0, 1.0f);
    gemm256_bt<unsigned short><<<gp, 512, 0, stream>>>(Xbf, Wkb, Kb, (int)SDIM, (int)SDIM, (int)(SDIM / 64), 0, 0, 0, 1.0f);
    gemm256_bt<unsigned short><<<gp, 512, 0, stream>>>(Xbf, Wvb, Vb, (int)SDIM, (int)SDIM, (int)(SDIM / 64), 0, 0, 0, 1.0f);

    // V -> V^T per batch (Vt overwrites Xbf region; X no longer needed)
    dim3 gt((unsigned)(SDIM / 64), (unsigned)(SEQ / 64), (unsigned)BATCH);
    transpose_bf16<<<gt, 256, 0, stream>>>(Vb, Vt, (int)SEQ, (int)SDIM);

    // scores: S[b] = Q[b] @ K[b]^T * (1/sqrt(D))
    const float scale = 1.0f / sqrtf((float)SDIM);
    dim3 gs((unsigned)(SEQ / 256), (unsigned)(SEQ / 256), (unsigned)BATCH);
    gemm256_bt<unsigned short><<<gs, 512, 0, stream>>>(Qb, Kb, Sb, (int)SEQ, (int)SDIM, (int)(SDIM / 64),
                                                       SEQ * SDIM, SEQ * SDIM, SEQ * SEQ, scale);

    // softmax rows in place
    softmax_inplace<<<(int)(BATCH * SEQ), 256, 0, stream>>>(Sb, (int)SEQ);

    // ctx[b] = P[b] @ Vt[b]^T : M=SEQ, N=SDIM, K=SEQ  (Ctx overwrites Qb)
    dim3 gc((unsigned)(SEQ / 256), (unsigned)(SDIM / 256), (unsigned)BATCH);
    gemm256_bt<unsigned short><<<gc, 512, 0, stream>>>(Sb, Vt, Ctx, (int)SDIM, (int)SEQ, (int)(SEQ / 64),
                                                       SEQ * SEQ, SDIM * SEQ, SEQ * SDIM, 1.0f);

    // out = Ctx @ Wo^T  (fp32 out, flat [8192,2048])
    gemm256_bt<float><<<gp, 512, 0, stream>>>(Ctx, Wob, out, (int)SDIM, (int)SDIM, (int)(SDIM / 64), 0, 0, 0, 1.0f);
}

// Round 6
// 582.053 us; speedup vs baseline: 1.4568x; 1.0298x over previous
//
#include <hip/hip_runtime.h>
#include <hip/hip_bf16.h>
#include <stdint.h>
#include <math.h>

typedef __attribute__((ext_vector_type(4))) float f32x4;
typedef __attribute__((ext_vector_type(8))) short s16x8;

typedef const __attribute__((address_space(1))) void* gas_ptr;
typedef __attribute__((address_space(3))) void* las_ptr;

__device__ __forceinline__ float bf2f(unsigned short u) {
    union { unsigned int i; float f; } x; x.i = ((unsigned int)u) << 16; return x.f;
}
__device__ __forceinline__ unsigned short f2bf(float f) {
    union { float f; unsigned int u; } x; x.f = f;
    unsigned int r = x.u + 0x7FFFu + ((x.u >> 16) & 1u);
    return (unsigned short)(r >> 16);
}

// ---------------- fp32 -> bf16 ----------------
__global__ __launch_bounds__(256) void cvt_f32_bf16(const float* __restrict__ src,
                                                    unsigned short* __restrict__ dst,
                                                    long n) {
    long i = ((long)blockIdx.x * 256 + threadIdx.x) * 8;
    if (i + 8 > n) return;
    f32x4 a = *(const f32x4*)(src + i);
    f32x4 b = *(const f32x4*)(src + i + 4);
    s16x8 o;
    o[0] = (short)f2bf(a[0]); o[1] = (short)f2bf(a[1]);
    o[2] = (short)f2bf(a[2]); o[3] = (short)f2bf(a[3]);
    o[4] = (short)f2bf(b[0]); o[5] = (short)f2bf(b[1]);
    o[6] = (short)f2bf(b[2]); o[7] = (short)f2bf(b[3]);
    *(s16x8*)(dst + i) = o;
}

// ============ 256x256 8-phase bf16 GEMM: C = alpha * A[M,K] @ B[N,K]^T ============
// Round-3 schedule with NO manual lgkmcnt waits: the compiler emits minimal
// counted lgkmcnt(N) per ds_read->MFMA dependency, so read completion overlaps
// MFMA issue/execution instead of batch-draining before each cluster (the
// r3/r5 serializer: manual lgkm(0) forced LDS and MFMA pipes to alternate,
// 5500 cyc/K-tile = 2800 LDS + 2480 MFMA fully serial).
// Correctness without manual lgkm: no ds_writes exist (staging is glds,
// vmcnt-tracked); own reads are compiler-tracked; every region's reads
// complete before that phase's last MFMA issues (>=2 barriers before any
// restage of the region); cross-tile staged-data visibility is gated by the
// counted boundary vmcnt(4) ("memory" asm - loads cannot hoist across).
// Stage schedule per tile t: P0->t+1.A1, P1->t+1.B1, P2->t+2.A0, P3->t+2.B0;
// ONE vmcnt per K-tile at the boundary: outstanding 12 -> vmcnt(4) lands all
// of tile t+1, keeps A0B0(t+2) in flight (T4: never drain in steady state).
// Swizzle (T2): element col ^= ((row&7)<<3); pre-swizzled global source for
// the linear global_load_lds dest + same XOR on ds_read address (rule 21).
template <typename CT>
__global__ __launch_bounds__(512, 2)
void gemm256_bt(const unsigned short* __restrict__ A,
                const unsigned short* __restrict__ B,
                CT* __restrict__ C,
                int N, int K, int nt,
                long sA, long sB, long sC, float alpha)
{
    A += (long)blockIdx.z * sA;
    B += (long)blockIdx.z * sB;
    C += (long)blockIdx.z * sC;

    __shared__ unsigned short L[2][2][2][128][64];   // 128 KiB

    const int t    = threadIdx.x;
    const int lane = t & 63;
    const int wid  = t >> 6;        // 0..7
    const int wm   = wid >> 2;      // 0..1
    const int wn   = wid & 3;       // 0..3
    const long brow = (long)blockIdx.x * 256;
    const long bcol = (long)blockIdx.y * 256;

    const int lr = lane & 15;
    const int hi = lane >> 4;            // 0..3
    const int sw = (lr & 7) << 3;        // ds_read swizzle (element units)

    // ---- staging precompute: thread t, chunk j handles linear u = t + 512j ----
    int voff[2];                      // LDS element offset u*8
    const unsigned short* pA[2][2];   // [sub][j] global src (pre-swizzled), k0=0
    const unsigned short* pB[2][2];
    {
        const unsigned short* Ab = A + brow * K;
        const unsigned short* Bb = B + bcol * K;
        #pragma unroll
        for (int j = 0; j < 2; ++j) {
            int u  = t + 512 * j;
            int ix = u >> 3;                       // phys row in [128][64] region
            int cg = u & 7;
            int cs = (cg * 8) ^ ((ix & 7) << 3);   // pre-swizzled col
            voff[j] = u * 8;
            long ra0 = ((long)(ix >> 6) << 7) | (0 << 6) | (ix & 63);
            long ra1 = ((long)(ix >> 6) << 7) | (1 << 6) | (ix & 63);
            long rb0 = ((long)(ix >> 5) << 6) | (0 << 5) | (ix & 31);
            long rb1 = ((long)(ix >> 5) << 6) | (1 << 5) | (ix & 31);
            pA[0][j] = Ab + ra0 * K + cs;
            pA[1][j] = Ab + ra1 * K + cs;
            pB[0][j] = Bb + rb0 * K + cs;
            pB[1][j] = Bb + rb1 * K + cs;
        }
    }

#define STAGE_A(H, KT) do { \
    _Pragma("unroll") \
    for (int j = 0; j < 2; ++j) \
        __builtin_amdgcn_global_load_lds((gas_ptr)(pA[H][j] + (long)(KT) * 64), \
            (las_ptr)(&L[(KT) & 1][0][H][0][0] + voff[j]), 16, 0, 0); \
} while (0)
#define STAGE_B(H, KT) do { \
    _Pragma("unroll") \
    for (int j = 0; j < 2; ++j) \
        __builtin_amdgcn_global_load_lds((gas_ptr)(pB[H][j] + (long)(KT) * 64), \
            (las_ptr)(&L[(KT) & 1][1][H][0][0] + voff[j]), 16, 0, 0); \
} while (0)

#define LOAD_AF(QM) do { \
    _Pragma("unroll") \
    for (int m = 0; m < 4; ++m) \
        _Pragma("unroll") \
        for (int kk = 0; kk < 2; ++kk) \
            af[m][kk] = *(const s16x8*)&L[cur][0][QM][wm * 64 + m * 16 + lr][(kk * 32 + hi * 8) ^ sw]; \
} while (0)
#define LOAD_BQ(DST, QN) do { \
    _Pragma("unroll") \
    for (int n = 0; n < 2; ++n) \
        _Pragma("unroll") \
        for (int kk = 0; kk < 2; ++kk) \
            DST[n][kk] = *(const s16x8*)&L[cur][1][QN][wn * 32 + n * 16 + lr][(kk * 32 + hi * 8) ^ sw]; \
} while (0)
#define MFMA_Q(QM, QN, BQ) do { \
    __builtin_amdgcn_s_setprio(1); \
    _Pragma("unroll") \
    for (int m = 0; m < 4; ++m) \
        _Pragma("unroll") \
        for (int n = 0; n < 2; ++n) \
            _Pragma("unroll") \
            for (int kk = 0; kk < 2; ++kk) \
                acc[(QM) * 4 + m][(QN) * 2 + n] = __builtin_amdgcn_mfma_f32_16x16x32_bf16( \
                    af[m][kk], BQ[n][kk], acc[(QM) * 4 + m][(QN) * 2 + n], 0, 0, 0); \
    __builtin_amdgcn_s_setprio(0); \
} while (0)

    f32x4 acc[8][4];
    #pragma unroll
    for (int m = 0; m < 8; ++m)
        #pragma unroll
        for (int n = 0; n < 4; ++n)
            acc[m][n] = {0.f, 0.f, 0.f, 0.f};

    // ---- prologue: tile0 all 4 halves + tile1 A0,B0; wait tile0 landed ----
    STAGE_A(0, 0); STAGE_B(0, 0); STAGE_A(1, 0); STAGE_B(1, 0);
    if (nt > 1) {
        STAGE_A(0, 1); STAGE_B(0, 1);
        asm volatile("s_waitcnt vmcnt(4)" ::: "memory");
    } else {
        asm volatile("s_waitcnt vmcnt(0)" ::: "memory");
    }
    __builtin_amdgcn_s_barrier();

    for (int kt = 0; kt < nt; ++kt) {
        const int cur = kt & 1;
        s16x8 af[4][2], bq0[2][2], bq1[2][2];

        // ---- P0: read A0 + B0 (12), stage t+1.A1, MFMA (0,0) ----
        LOAD_AF(0);
        LOAD_BQ(bq0, 0);
        if (kt + 1 < nt) STAGE_A(1, kt + 1);
        __builtin_amdgcn_s_barrier();
        MFMA_Q(0, 0, bq0);
        __builtin_amdgcn_s_barrier();

        // ---- P1: read B1 (4), stage t+1.B1, MFMA (0,1) [af reused] ----
        LOAD_BQ(bq1, 1);
        if (kt + 1 < nt) STAGE_B(1, kt + 1);
        __builtin_amdgcn_s_barrier();
        MFMA_Q(0, 1, bq1);
        __builtin_amdgcn_s_barrier();

        // ---- P2: read A1 (8), stage t+2.A0, MFMA (1,1) [bq1 reused] ----
        LOAD_AF(1);
        if (kt + 2 < nt) STAGE_A(0, kt + 2);
        __builtin_amdgcn_s_barrier();
        MFMA_Q(1, 1, bq1);
        __builtin_amdgcn_s_barrier();

        // ---- P3: no reads, stage t+2.B0, MFMA (1,0) [af + bq0 reused] ----
        if (kt + 2 < nt) STAGE_B(0, kt + 2);
        __builtin_amdgcn_s_barrier();
        MFMA_Q(1, 0, bq0);

        // tile boundary: tile t+1 fully landed; keep A0B0(t+2) in flight
        if (kt + 1 < nt) {
            if (kt + 2 < nt) asm volatile("s_waitcnt vmcnt(4)" ::: "memory");
            else             asm volatile("s_waitcnt vmcnt(0)" ::: "memory");
            __builtin_amdgcn_s_barrier();
        }
    }
#undef STAGE_A
#undef STAGE_B
#undef LOAD_AF
#undef LOAD_BQ
#undef MFMA_Q

    // ---- epilogue: C[row][col], row = 16*am + hi*4 + i, col = 16*an + lr ----
    #pragma unroll
    for (int m = 0; m < 8; ++m) {
        #pragma unroll
        for (int n = 0; n < 4; ++n) {
            #pragma unroll
            for (int i = 0; i < 4; ++i) {
                long row = brow + wm * 128 + m * 16 + hi * 4 + i;
                long col = bcol + wn * 64 + n * 16 + lr;
                float vv = acc[m][n][i] * alpha;
                if constexpr (sizeof(CT) == 2) {
                    ((unsigned short*)C)[row * (long)N + col] = f2bf(vv);
                } else {
                    ((float*)C)[row * (long)N + col] = vv;
                }
            }
        }
    }
}

// ---------------- bf16 transpose: dst[c][r] = src[r][c], per-batch ----------------
__global__ __launch_bounds__(256) void transpose_bf16(const unsigned short* __restrict__ src,
                                                      unsigned short* __restrict__ dst,
                                                      int srows, int scols) {
    __shared__ unsigned short tile[64][66];
    const long bofs = (long)blockIdx.z * srows * scols;
    const unsigned short* s = src + bofs;
    unsigned short* d = dst + bofs;
    const int c0 = blockIdx.x * 64;
    const int r0 = blockIdx.y * 64;
    const int tx = threadIdx.x & 15;
    const int ty = threadIdx.x >> 4;

    #pragma unroll
    for (int k = 0; k < 4; ++k) {
        int r = ty + 16 * k;
        ushort4 v = *(const ushort4*)(s + (long)(r0 + r) * scols + c0 + tx * 4);
        tile[r][tx * 4 + 0] = v.x; tile[r][tx * 4 + 1] = v.y;
        tile[r][tx * 4 + 2] = v.z; tile[r][tx * 4 + 3] = v.w;
    }
    __syncthreads();
    #pragma unroll
    for (int k = 0; k < 4; ++k) {
        int dr = ty + 16 * k;
        ushort4 v;
        v.x = tile[tx * 4 + 0][dr]; v.y = tile[tx * 4 + 1][dr];
        v.z = tile[tx * 4 + 2][dr]; v.w = tile[tx * 4 + 3][dr];
        *(ushort4*)(d + (long)(c0 + dr) * srows + r0 + tx * 4) = v;
    }
}

// ---------------- row softmax, in place, bf16, ncols = 4096 ----------------
__global__ __launch_bounds__(256) void softmax_inplace(unsigned short* __restrict__ S, int ncols) {
    const long row = blockIdx.x;
    unsigned short* p = S + row * (long)ncols;
    const int t = threadIdx.x;
    const int wid = t >> 6;

    ushort4 raw[4];
    const ushort4* pv = (const ushort4*)(p + t * 16);
    #pragma unroll
    for (int i = 0; i < 4; ++i) raw[i] = pv[i];

    float v[16];
    float mx = -1e30f;
    #pragma unroll
    for (int i = 0; i < 4; ++i) {
        v[4*i+0] = bf2f(raw[i].x); v[4*i+1] = bf2f(raw[i].y);
        v[4*i+2] = bf2f(raw[i].z); v[4*i+3] = bf2f(raw[i].w);
    }
    #pragma unroll
    for (int i = 0; i < 16; ++i) mx = fmaxf(mx, v[i]);
    #pragma unroll
    for (int off = 32; off > 0; off >>= 1) mx = fmaxf(mx, __shfl_xor(mx, off));

    __shared__ float red[8];
    if ((t & 63) == 0) red[wid] = mx;
    __syncthreads();
    mx = fmaxf(fmaxf(red[0], red[1]), fmaxf(red[2], red[3]));

    float sum = 0.f;
    #pragma unroll
    for (int i = 0; i < 16; ++i) { v[i] = __expf(v[i] - mx); sum += v[i]; }
    #pragma unroll
    for (int off = 32; off > 0; off >>= 1) sum += __shfl_xor(sum, off);
    __syncthreads();
    if ((t & 63) == 0) red[4 + wid] = sum;
    __syncthreads();
    sum = red[4] + red[5] + red[6] + red[7];
    const float inv = 1.0f / sum;

    ushort4* po = (ushort4*)(p + t * 16);
    #pragma unroll
    for (int i = 0; i < 4; ++i) {
        ushort4 o;
        o.x = f2bf(v[4*i+0] * inv); o.y = f2bf(v[4*i+1] * inv);
        o.z = f2bf(v[4*i+2] * inv); o.w = f2bf(v[4*i+3] * inv);
        po[i] = o;
    }
}

extern "C" void kernel_launch(void* const* d_in, const int* in_sizes, int n_in,
                              void* d_out, int out_size, void* d_ws, size_t ws_size,
                              hipStream_t stream) {
    const float* x  = (const float*)d_in[0];
    const float* wq = (const float*)d_in[1];
    const float* wk = (const float*)d_in[2];
    const float* wv = (const float*)d_in[3];
    const float* wo = (const float*)d_in[4];
    float* out = (float*)d_out;

    const long SDIM = 2048, SEQ = 4096, BATCH = 2;
    const long MS = BATCH * SEQ;       // 8192
    const long XN = MS * SDIM;         // 16,777,216
    const long WN = SDIM * SDIM;       // 4,194,304

    unsigned short* ws  = (unsigned short*)d_ws;
    unsigned short* Xbf = ws;               // XN elems (reused as Vt later)
    unsigned short* Wqb = ws + XN;
    unsigned short* Wkb = Wqb + WN;
    unsigned short* Wvb = Wkb + WN;
    unsigned short* Wob = Wvb + WN;
    unsigned short* Qb  = Wob + WN;         // XN (reused as Ctx later)
    unsigned short* Kb  = Qb + XN;
    unsigned short* Vb  = Kb + XN;
    unsigned short* Sb  = Vb + XN;          // 2*4096*4096 bf16
    unsigned short* Vt  = Xbf;
    unsigned short* Ctx = Qb;

    // fp32 -> bf16 conversions
    cvt_f32_bf16<<<(int)(XN / 2048), 256, 0, stream>>>(x,  Xbf, XN);
    cvt_f32_bf16<<<(int)(WN / 2048), 256, 0, stream>>>(wq, Wqb, WN);
    cvt_f32_bf16<<<(int)(WN / 2048), 256, 0, stream>>>(wk, Wkb, WN);
    cvt_f32_bf16<<<(int)(WN / 2048), 256, 0, stream>>>(wv, Wvb, WN);
    cvt_f32_bf16<<<(int)(WN / 2048), 256, 0, stream>>>(wo, Wob, WN);

    // projections: [8192,2048] = Xbf @ W^T
    dim3 gp((unsigned)(MS / 256), (unsigned)(SDIM / 256), 1);
    gemm256_bt<unsigned short><<<gp, 512, 0, stream>>>(Xbf, Wqb, Qb, (int)SDIM, (int)SDIM, (int)(SDIM / 64), 0, 0, 0, 1.0f);
    gemm256_bt<unsigned short><<<gp, 512, 0, stream>>>(Xbf, Wkb, Kb, (int)SDIM, (int)SDIM, (int)(SDIM / 64), 0, 0, 0, 1.0f);
    gemm256_bt<unsigned short><<<gp, 512, 0, stream>>>(Xbf, Wvb, Vb, (int)SDIM, (int)SDIM, (int)(SDIM / 64), 0, 0, 0, 1.0f);

    // V -> V^T per batch (Vt overwrites Xbf region; X no longer needed)
    dim3 gt((unsigned)(SDIM / 64), (unsigned)(SEQ / 64), (unsigned)BATCH);
    transpose_bf16<<<gt, 256, 0, stream>>>(Vb, Vt, (int)SEQ, (int)SDIM);

    // scores: S[b] = Q[b] @ K[b]^T * (1/sqrt(D))
    const float scale = 1.0f / sqrtf((float)SDIM);
    dim3 gs((unsigned)(SEQ / 256), (unsigned)(SEQ / 256), (unsigned)BATCH);
    gemm256_bt<unsigned short><<<gs, 512, 0, stream>>>(Qb, Kb, Sb, (int)SEQ, (int)SDIM, (int)(SDIM / 64),
                                                       SEQ * SDIM, SEQ * SDIM, SEQ * SEQ, scale);

    // softmax rows in place
    softmax_inplace<<<(int)(BATCH * SEQ), 256, 0, stream>>>(Sb, (int)SEQ);

    // ctx[b] = P[b] @ Vt[b]^T : M=SEQ, N=SDIM, K=SEQ  (Ctx overwrites Qb)
    dim3 gc((unsigned)(SEQ / 256), (unsigned)(SDIM / 256), (unsigned)BATCH);
    gemm256_bt<unsigned short><<<gc, 512, 0, stream>>>(Sb, Vt, Ctx, (int)SDIM, (int)SEQ, (int)(SEQ / 64),
                                                       SEQ * SEQ, SDIM * SEQ, SEQ * SDIM, 1.0f);

    // out = Ctx @ Wo^T  (fp32 out, flat [8192,2048])
    gemm256_bt<float><<<gp, 512, 0, stream>>>(Ctx, Wob, out, (int)SDIM, (int)SDIM, (int)(SDIM / 64), 0, 0, 0, 1.0f);
}

// Round 7
// 570.065 us; speedup vs baseline: 1.4875x; 1.0210x over previous
//
#include <hip/hip_runtime.h>
#include <hip/hip_bf16.h>
#include <stdint.h>
#include <math.h>

typedef __attribute__((ext_vector_type(4))) float f32x4;
typedef __attribute__((ext_vector_type(8))) short s16x8;

typedef const __attribute__((address_space(1))) void* gas_ptr;
typedef __attribute__((address_space(3))) void* las_ptr;

__device__ __forceinline__ float bf2f(unsigned short u) {
    union { unsigned int i; float f; } x; x.i = ((unsigned int)u) << 16; return x.f;
}
__device__ __forceinline__ unsigned short f2bf(float f) {
    union { float f; unsigned int u; } x; x.f = f;
    unsigned int r = x.u + 0x7FFFu + ((x.u >> 16) & 1u);
    return (unsigned short)(r >> 16);
}

// ---------------- fp32 -> bf16 ----------------
__global__ __launch_bounds__(256) void cvt_f32_bf16(const float* __restrict__ src,
                                                    unsigned short* __restrict__ dst,
                                                    long n) {
    long i = ((long)blockIdx.x * 256 + threadIdx.x) * 8;
    if (i + 8 > n) return;
    f32x4 a = *(const f32x4*)(src + i);
    f32x4 b = *(const f32x4*)(src + i + 4);
    s16x8 o;
    o[0] = (short)f2bf(a[0]); o[1] = (short)f2bf(a[1]);
    o[2] = (short)f2bf(a[2]); o[3] = (short)f2bf(a[3]);
    o[4] = (short)f2bf(b[0]); o[5] = (short)f2bf(b[1]);
    o[6] = (short)f2bf(b[2]); o[7] = (short)f2bf(b[3]);
    *(s16x8*)(dst + i) = o;
}

// ============ 256x256 8-phase bf16 GEMM: C = alpha * A[M,K] @ B[N,K]^T ============
// Round-6 skeleton (no manual lgkm waits; compiler emits minimal counted
// lgkmcnt per ds_read->MFMA dep) + WAR-FREE FRAGMENT REGISTERS:
// every MFMA in a cluster reads the af set, so a cluster "holds" its operand
// registers for the full ~620-cyc drain; r3-r6 let the NEXT phase's ds_reads
// overwrite exactly those registers (P2's LOAD_AF vs P1's draining MFMAs;
// P0(t+1)'s bq0 load vs P3(t)'s draining MFMAs), so read writeback serialized
// behind the matrix pipe -> measured 5290 cyc/K-tile = LDS + MFMA serial.
// Fix: af0 (A-sub0) and af1 (A-sub1) are distinct sets; bq0 is double-buffered
// by tile parity (kt unrolled x2, compile-time). Audit: no phase's reads touch
// any register read by the immediately-preceding MFMA cluster; clusters >=2
// phases old have drained. No sched_barrier pins (r4/m141 lesson).
// Stage schedule per tile t: P0->t+1.A1, P1->t+1.B1, P2->t+2.A0, P3->t+2.B0;
// one counted vmcnt(4) per K-tile at the boundary (T4). Swizzle (T2):
// col ^= ((row&7)<<3), pre-swizzled global source + same XOR on ds_read.
template <typename CT>
__global__ __launch_bounds__(512, 2)
void gemm256_bt(const unsigned short* __restrict__ A,
                const unsigned short* __restrict__ B,
                CT* __restrict__ C,
                int N, int K, int nt,
                long sA, long sB, long sC, float alpha)
{
    A += (long)blockIdx.z * sA;
    B += (long)blockIdx.z * sB;
    C += (long)blockIdx.z * sC;

    __shared__ unsigned short L[2][2][2][128][64];   // 128 KiB

    const int t    = threadIdx.x;
    const int lane = t & 63;
    const int wid  = t >> 6;        // 0..7
    const int wm   = wid >> 2;      // 0..1
    const int wn   = wid & 3;       // 0..3
    const long brow = (long)blockIdx.x * 256;
    const long bcol = (long)blockIdx.y * 256;

    const int lr = lane & 15;
    const int hi = lane >> 4;            // 0..3
    const int sw = (lr & 7) << 3;        // ds_read swizzle (element units)

    // ---- staging precompute: thread t, chunk j handles linear u = t + 512j ----
    int voff[2];                      // LDS element offset u*8
    const unsigned short* pA[2][2];   // [sub][j] global src (pre-swizzled), k0=0
    const unsigned short* pB[2][2];
    {
        const unsigned short* Ab = A + brow * K;
        const unsigned short* Bb = B + bcol * K;
        #pragma unroll
        for (int j = 0; j < 2; ++j) {
            int u  = t + 512 * j;
            int ix = u >> 3;                       // phys row in [128][64] region
            int cg = u & 7;
            int cs = (cg * 8) ^ ((ix & 7) << 3);   // pre-swizzled col
            voff[j] = u * 8;
            long ra0 = ((long)(ix >> 6) << 7) | (0 << 6) | (ix & 63);
            long ra1 = ((long)(ix >> 6) << 7) | (1 << 6) | (ix & 63);
            long rb0 = ((long)(ix >> 5) << 6) | (0 << 5) | (ix & 31);
            long rb1 = ((long)(ix >> 5) << 6) | (1 << 5) | (ix & 31);
            pA[0][j] = Ab + ra0 * K + cs;
            pA[1][j] = Ab + ra1 * K + cs;
            pB[0][j] = Bb + rb0 * K + cs;
            pB[1][j] = Bb + rb1 * K + cs;
        }
    }

#define STAGE_A(H, KT) do { \
    _Pragma("unroll") \
    for (int j = 0; j < 2; ++j) \
        __builtin_amdgcn_global_load_lds((gas_ptr)(pA[H][j] + (long)(KT) * 64), \
            (las_ptr)(&L[(KT) & 1][0][H][0][0] + voff[j]), 16, 0, 0); \
} while (0)
#define STAGE_B(H, KT) do { \
    _Pragma("unroll") \
    for (int j = 0; j < 2; ++j) \
        __builtin_amdgcn_global_load_lds((gas_ptr)(pB[H][j] + (long)(KT) * 64), \
            (las_ptr)(&L[(KT) & 1][1][H][0][0] + voff[j]), 16, 0, 0); \
} while (0)

#define LOAD_AF(DST, CUR, QM) do { \
    _Pragma("unroll") \
    for (int m = 0; m < 4; ++m) \
        _Pragma("unroll") \
        for (int kk = 0; kk < 2; ++kk) \
            DST[m][kk] = *(const s16x8*)&L[CUR][0][QM][wm * 64 + m * 16 + lr][(kk * 32 + hi * 8) ^ sw]; \
} while (0)
#define LOAD_BQ(DST, CUR, QN) do { \
    _Pragma("unroll") \
    for (int n = 0; n < 2; ++n) \
        _Pragma("unroll") \
        for (int kk = 0; kk < 2; ++kk) \
            DST[n][kk] = *(const s16x8*)&L[CUR][1][QN][wn * 32 + n * 16 + lr][(kk * 32 + hi * 8) ^ sw]; \
} while (0)
#define MFMA_Q(QM, QN, AF, BQ) do { \
    __builtin_amdgcn_s_setprio(1); \
    _Pragma("unroll") \
    for (int m = 0; m < 4; ++m) \
        _Pragma("unroll") \
        for (int n = 0; n < 2; ++n) \
            _Pragma("unroll") \
            for (int kk = 0; kk < 2; ++kk) \
                acc[(QM) * 4 + m][(QN) * 2 + n] = __builtin_amdgcn_mfma_f32_16x16x32_bf16( \
                    AF[m][kk], BQ[n][kk], acc[(QM) * 4 + m][(QN) * 2 + n], 0, 0, 0); \
    __builtin_amdgcn_s_setprio(0); \
} while (0)

// One K-tile, CUR = compile-time LDS buffer parity, BQ0 = parity-owned bq0 set.
#define TILE_BODY(CUR, KTE, BQ0) do { \
    const int kt_ = (KTE); \
    /* ---- P0: read A0->af0, B0->BQ0, stage t+1.A1, MFMA (0,0) ---- */ \
    LOAD_AF(af0, CUR, 0); \
    LOAD_BQ(BQ0, CUR, 0); \
    if (kt_ + 1 < nt) STAGE_A(1, kt_ + 1); \
    __builtin_amdgcn_s_barrier(); \
    MFMA_Q(0, 0, af0, BQ0); \
    __builtin_amdgcn_s_barrier(); \
    /* ---- P1: read B1->bq1, stage t+1.B1, MFMA (0,1) ---- */ \
    LOAD_BQ(bq1, CUR, 1); \
    if (kt_ + 1 < nt) STAGE_B(1, kt_ + 1); \
    __builtin_amdgcn_s_barrier(); \
    MFMA_Q(0, 1, af0, bq1); \
    __builtin_amdgcn_s_barrier(); \
    /* ---- P2: read A1->af1 (no WAR: af1 != af0), stage t+2.A0, MFMA (1,1) ---- */ \
    LOAD_AF(af1, CUR, 1); \
    if (kt_ + 2 < nt) STAGE_A(0, kt_ + 2); \
    __builtin_amdgcn_s_barrier(); \
    MFMA_Q(1, 1, af1, bq1); \
    __builtin_amdgcn_s_barrier(); \
    /* ---- P3: no reads, stage t+2.B0, MFMA (1,0) ---- */ \
    if (kt_ + 2 < nt) STAGE_B(0, kt_ + 2); \
    __builtin_amdgcn_s_barrier(); \
    MFMA_Q(1, 0, af1, BQ0); \
    /* boundary: tile t+1 landed; keep A0B0(t+2) in flight */ \
    if (kt_ + 1 < nt) { \
        if (kt_ + 2 < nt) asm volatile("s_waitcnt vmcnt(4)" ::: "memory"); \
        else              asm volatile("s_waitcnt vmcnt(0)" ::: "memory"); \
        __builtin_amdgcn_s_barrier(); \
    } \
} while (0)

    f32x4 acc[8][4];
    #pragma unroll
    for (int m = 0; m < 8; ++m)
        #pragma unroll
        for (int n = 0; n < 4; ++n)
            acc[m][n] = {0.f, 0.f, 0.f, 0.f};

    s16x8 af0[4][2], af1[4][2], bq0E[2][2], bq0O[2][2], bq1[2][2];

    // ---- prologue: tile0 all 4 halves + tile1 A0,B0; wait tile0 landed ----
    STAGE_A(0, 0); STAGE_B(0, 0); STAGE_A(1, 0); STAGE_B(1, 0);
    if (nt > 1) {
        STAGE_A(0, 1); STAGE_B(0, 1);
        asm volatile("s_waitcnt vmcnt(4)" ::: "memory");
    } else {
        asm volatile("s_waitcnt vmcnt(0)" ::: "memory");
    }
    __builtin_amdgcn_s_barrier();

    // nt is even for all shapes used here (K % 128 == 0).
    for (int kt = 0; kt < nt; kt += 2) {
        TILE_BODY(0, kt, bq0E);
        if (kt + 1 < nt) TILE_BODY(1, kt + 1, bq0O);
    }
#undef TILE_BODY
#undef STAGE_A
#undef STAGE_B
#undef LOAD_AF
#undef LOAD_BQ
#undef MFMA_Q

    // ---- epilogue: C[row][col], row = 16*am + hi*4 + i, col = 16*an + lr ----
    #pragma unroll
    for (int m = 0; m < 8; ++m) {
        #pragma unroll
        for (int n = 0; n < 4; ++n) {
            #pragma unroll
            for (int i = 0; i < 4; ++i) {
                long row = brow + wm * 128 + m * 16 + hi * 4 + i;
                long col = bcol + wn * 64 + n * 16 + lr;
                float vv = acc[m][n][i] * alpha;
                if constexpr (sizeof(CT) == 2) {
                    ((unsigned short*)C)[row * (long)N + col] = f2bf(vv);
                } else {
                    ((float*)C)[row * (long)N + col] = vv;
                }
            }
        }
    }
}

// ---------------- bf16 transpose: dst[c][r] = src[r][c], per-batch ----------------
__global__ __launch_bounds__(256) void transpose_bf16(const unsigned short* __restrict__ src,
                                                      unsigned short* __restrict__ dst,
                                                      int srows, int scols) {
    __shared__ unsigned short tile[64][66];
    const long bofs = (long)blockIdx.z * srows * scols;
    const unsigned short* s = src + bofs;
    unsigned short* d = dst + bofs;
    const int c0 = blockIdx.x * 64;
    const int r0 = blockIdx.y * 64;
    const int tx = threadIdx.x & 15;
    const int ty = threadIdx.x >> 4;

    #pragma unroll
    for (int k = 0; k < 4; ++k) {
        int r = ty + 16 * k;
        ushort4 v = *(const ushort4*)(s + (long)(r0 + r) * scols + c0 + tx * 4);
        tile[r][tx * 4 + 0] = v.x; tile[r][tx * 4 + 1] = v.y;
        tile[r][tx * 4 + 2] = v.z; tile[r][tx * 4 + 3] = v.w;
    }
    __syncthreads();
    #pragma unroll
    for (int k = 0; k < 4; ++k) {
        int dr = ty + 16 * k;
        ushort4 v;
        v.x = tile[tx * 4 + 0][dr]; v.y = tile[tx * 4 + 1][dr];
        v.z = tile[tx * 4 + 2][dr]; v.w = tile[tx * 4 + 3][dr];
        *(ushort4*)(d + (long)(c0 + dr) * srows + r0 + tx * 4) = v;
    }
}

// ---------------- row softmax, in place, bf16, ncols = 4096 ----------------
__global__ __launch_bounds__(256) void softmax_inplace(unsigned short* __restrict__ S, int ncols) {
    const long row = blockIdx.x;
    unsigned short* p = S + row * (long)ncols;
    const int t = threadIdx.x;
    const int wid = t >> 6;

    ushort4 raw[4];
    const ushort4* pv = (const ushort4*)(p + t * 16);
    #pragma unroll
    for (int i = 0; i < 4; ++i) raw[i] = pv[i];

    float v[16];
    float mx = -1e30f;
    #pragma unroll
    for (int i = 0; i < 4; ++i) {
        v[4*i+0] = bf2f(raw[i].x); v[4*i+1] = bf2f(raw[i].y);
        v[4*i+2] = bf2f(raw[i].z); v[4*i+3] = bf2f(raw[i].w);
    }
    #pragma unroll
    for (int i = 0; i < 16; ++i) mx = fmaxf(mx, v[i]);
    #pragma unroll
    for (int off = 32; off > 0; off >>= 1) mx = fmaxf(mx, __shfl_xor(mx, off));

    __shared__ float red[8];
    if ((t & 63) == 0) red[wid] = mx;
    __syncthreads();
    mx = fmaxf(fmaxf(red[0], red[1]), fmaxf(red[2], red[3]));

    float sum = 0.f;
    #pragma unroll
    for (int i = 0; i < 16; ++i) { v[i] = __expf(v[i] - mx); sum += v[i]; }
    #pragma unroll
    for (int off = 32; off > 0; off >>= 1) sum += __shfl_xor(sum, off);
    __syncthreads();
    if ((t & 63) == 0) red[4 + wid] = sum;
    __syncthreads();
    sum = red[4] + red[5] + red[6] + red[7];
    const float inv = 1.0f / sum;

    ushort4* po = (ushort4*)(p + t * 16);
    #pragma unroll
    for (int i = 0; i < 4; ++i) {
        ushort4 o;
        o.x = f2bf(v[4*i+0] * inv); o.y = f2bf(v[4*i+1] * inv);
        o.z = f2bf(v[4*i+2] * inv); o.w = f2bf(v[4*i+3] * inv);
        po[i] = o;
    }
}

extern "C" void kernel_launch(void* const* d_in, const int* in_sizes, int n_in,
                              void* d_out, int out_size, void* d_ws, size_t ws_size,
                              hipStream_t stream) {
    const float* x  = (const float*)d_in[0];
    const float* wq = (const float*)d_in[1];
    const float* wk = (const float*)d_in[2];
    const float* wv = (const float*)d_in[3];
    const float* wo = (const float*)d_in[4];
    float* out = (float*)d_out;

    const long SDIM = 2048, SEQ = 4096, BATCH = 2;
    const long MS = BATCH * SEQ;       // 8192
    const long XN = MS * SDIM;         // 16,777,216
    const long WN = SDIM * SDIM;       // 4,194,304

    unsigned short* ws  = (unsigned short*)d_ws;
    unsigned short* Xbf = ws;               // XN elems (reused as Vt later)
    unsigned short* Wqb = ws + XN;
    unsigned short* Wkb = Wqb + WN;
    unsigned short* Wvb = Wkb + WN;
    unsigned short* Wob = Wvb + WN;
    unsigned short* Qb  = Wob + WN;         // XN (reused as Ctx later)
    unsigned short* Kb  = Qb + XN;
    unsigned short* Vb  = Kb + XN;
    unsigned short* Sb  = Vb + XN;          // 2*4096*4096 bf16
    unsigned short* Vt  = Xbf;
    unsigned short* Ctx = Qb;

    // fp32 -> bf16 conversions
    cvt_f32_bf16<<<(int)(XN / 2048), 256, 0, stream>>>(x,  Xbf, XN);
    cvt_f32_bf16<<<(int)(WN / 2048), 256, 0, stream>>>(wq, Wqb, WN);
    cvt_f32_bf16<<<(int)(WN / 2048), 256, 0, stream>>>(wk, Wkb, WN);
    cvt_f32_bf16<<<(int)(WN / 2048), 256, 0, stream>>>(wv, Wvb, WN);
    cvt_f32_bf16<<<(int)(WN / 2048), 256, 0, stream>>>(wo, Wob, WN);

    // projections: [8192,2048] = Xbf @ W^T
    dim3 gp((unsigned)(MS / 256), (unsigned)(SDIM / 256), 1);
    gemm256_bt<unsigned short><<<gp, 512, 0, stream>>>(Xbf, Wqb, Qb, (int)SDIM, (int)SDIM, (int)(SDIM / 64), 0, 0, 0, 1.0f);
    gemm256_bt<unsigned short><<<gp, 512, 0, stream>>>(Xbf, Wkb, Kb, (int)SDIM, (int)SDIM, (int)(SDIM / 64), 0, 0, 0, 1.0f);
    gemm256_bt<unsigned short><<<gp, 512, 0, stream>>>(Xbf, Wvb, Vb, (int)SDIM, (int)SDIM, (int)(SDIM / 64), 0, 0, 0, 1.0f);

    // V -> V^T per batch (Vt overwrites Xbf region; X no longer needed)
    dim3 gt((unsigned)(SDIM / 64), (unsigned)(SEQ / 64), (unsigned)BATCH);
    transpose_bf16<<<gt, 256, 0, stream>>>(Vb, Vt, (int)SEQ, (int)SDIM);

    // scores: S[b] = Q[b] @ K[b]^T * (1/sqrt(D))
    const float scale = 1.0f / sqrtf((float)SDIM);
    dim3 gs((unsigned)(SEQ / 256), (unsigned)(SEQ / 256), (unsigned)BATCH);
    gemm256_bt<unsigned short><<<gs, 512, 0, stream>>>(Qb, Kb, Sb, (int)SEQ, (int)SDIM, (int)(SDIM / 64),
                                                       SEQ * SDIM, SEQ * SDIM, SEQ * SEQ, scale);

    // softmax rows in place
    softmax_inplace<<<(int)(BATCH * SEQ), 256, 0, stream>>>(Sb, (int)SEQ);

    // ctx[b] = P[b] @ Vt[b]^T : M=SEQ, N=SDIM, K=SEQ  (Ctx overwrites Qb)
    dim3 gc((unsigned)(SEQ / 256), (unsigned)(SDIM / 256), (unsigned)BATCH);
    gemm256_bt<unsigned short><<<gc, 512, 0, stream>>>(Sb, Vt, Ctx, (int)SDIM, (int)SEQ, (int)(SEQ / 64),
                                                       SEQ * SEQ, SDIM * SEQ, SEQ * SDIM, 1.0f);

    // out = Ctx @ Wo^T  (fp32 out, flat [8192,2048])
    gemm256_bt<float><<<gp, 512, 0, stream>>>(Ctx, Wob, out, (int)SDIM, (int)SDIM, (int)(SDIM / 64), 0, 0, 0, 1.0f);
}

// Round 8
// 550.532 us; speedup vs baseline: 1.5402x; 1.0355x over previous
//
#include <hip/hip_runtime.h>
#include <hip/hip_bf16.h>
#include <stdint.h>
#include <math.h>

typedef __attribute__((ext_vector_type(4))) float f32x4;
typedef __attribute__((ext_vector_type(8))) short s16x8;

typedef const __attribute__((address_space(1))) void* gas_ptr;
typedef __attribute__((address_space(3))) void* las_ptr;

__device__ __forceinline__ float bf2f(unsigned short u) {
    union { unsigned int i; float f; } x; x.i = ((unsigned int)u) << 16; return x.f;
}
__device__ __forceinline__ unsigned short f2bf(float f) {
    union { float f; unsigned int u; } x; x.f = f;
    unsigned int r = x.u + 0x7FFFu + ((x.u >> 16) & 1u);
    return (unsigned short)(r >> 16);
}

// ---------------- fp32 -> bf16 ----------------
__global__ __launch_bounds__(256) void cvt_f32_bf16(const float* __restrict__ src,
                                                    unsigned short* __restrict__ dst,
                                                    long n) {
    long i = ((long)blockIdx.x * 256 + threadIdx.x) * 8;
    if (i + 8 > n) return;
    f32x4 a = *(const f32x4*)(src + i);
    f32x4 b = *(const f32x4*)(src + i + 4);
    s16x8 o;
    o[0] = (short)f2bf(a[0]); o[1] = (short)f2bf(a[1]);
    o[2] = (short)f2bf(a[2]); o[3] = (short)f2bf(a[3]);
    o[4] = (short)f2bf(b[0]); o[5] = (short)f2bf(b[1]);
    o[6] = (short)f2bf(b[2]); o[7] = (short)f2bf(b[3]);
    *(s16x8*)(dst + i) = o;
}

// ============ 256x256 bf16 GEMM, 2-half K-tile, minimal barriers ============
// r3-r7 lesson: 9 barriers/K-tile lock-step all 8 waves -> LDS reads (2816cy)
// and MFMA (2483cy) run SERIALLY (measured ~5200cy/K-tile). This version keeps
// only the 2 barriers correctness requires, so waves free-run and one wave's
// MFMA drain overlaps another's read burst (m114 max-not-sum mechanism).
//   H0: read A0,B0,B1 | stage (t+1).A1,B1 -> buf^1 (race-free: those regions'
//       readers finished before last boundary) | MFMA (0,0),(0,1) | MID BARRIER
//       (required: H1 stages into buf[cur].A0/B0 which H0 reads; every wave's
//       H0 reads are drained before its MFMAs issue, so at the barrier all
//       reads are done; the glds lands >=900cy later, next read >=1 tile away)
//   H1: read A1 | stage (t+2).A0,B0 -> buf[cur] | MFMA (1,1),(1,0)
//   boundary: vmcnt(4) + barrier. Ledger: queue = [A0B0(t+1) 4][A1B1(t+1) 4]
//       [A0B0(t+2) 4] -> drains 8 oldest = tile t+1 complete, keeps t+2's 4
//       in flight (T4, never 0 in steady state). Tail kt+2>=nt: vmcnt(0) once.
// No manual lgkmcnt: compiler emits minimal counted waits per ds_read->MFMA.
// WAR: bq0 parity-doubled (loaded at H0(t+1) while (1,0) of t drains);
// H1 cluster ordered (1,1) first so bq1 drains before its t+1 reload.
// Swizzle (T2): col ^= ((row&7)<<3), pre-swizzled global src + same XOR on read.
// T1: XCD-aware blockIdx.x swizzle (all grids have gridDim.x % 8 == 0).
template <typename CT>
__global__ __launch_bounds__(512, 2)
void gemm256_bt(const unsigned short* __restrict__ A,
                const unsigned short* __restrict__ B,
                CT* __restrict__ C,
                int N, int K, int nt,
                long sA, long sB, long sC, float alpha)
{
    A += (long)blockIdx.z * sA;
    B += (long)blockIdx.z * sB;
    C += (long)blockIdx.z * sC;

    __shared__ unsigned short L[2][2][2][128][64];   // 128 KiB

    const int t    = threadIdx.x;
    const int lane = t & 63;
    const int wid  = t >> 6;        // 0..7
    const int wm   = wid >> 2;      // 0..1
    const int wn   = wid & 3;       // 0..3

    // T1: XCD swizzle on x (M-tiles): XCD k gets a contiguous chunk of rows.
    const int cpx = (int)gridDim.x >> 3;
    const int bx  = ((int)blockIdx.x & 7) * cpx + ((int)blockIdx.x >> 3);
    const long brow = (long)bx * 256;
    const long bcol = (long)blockIdx.y * 256;

    const int lr = lane & 15;
    const int hi = lane >> 4;            // 0..3
    const int sw = (lr & 7) << 3;        // ds_read swizzle (element units)

    // ---- staging precompute: thread t, chunk j handles linear u = t + 512j ----
    int voff[2];                      // LDS element offset u*8
    const unsigned short* pA[2][2];   // [sub][j] global src (pre-swizzled), k0=0
    const unsigned short* pB[2][2];
    {
        const unsigned short* Ab = A + brow * K;
        const unsigned short* Bb = B + bcol * K;
        #pragma unroll
        for (int j = 0; j < 2; ++j) {
            int u  = t + 512 * j;
            int ix = u >> 3;                       // phys row in [128][64] region
            int cg = u & 7;
            int cs = (cg * 8) ^ ((ix & 7) << 3);   // pre-swizzled col
            voff[j] = u * 8;
            long ra0 = ((long)(ix >> 6) << 7) | (0 << 6) | (ix & 63);
            long ra1 = ((long)(ix >> 6) << 7) | (1 << 6) | (ix & 63);
            long rb0 = ((long)(ix >> 5) << 6) | (0 << 5) | (ix & 31);
            long rb1 = ((long)(ix >> 5) << 6) | (1 << 5) | (ix & 31);
            pA[0][j] = Ab + ra0 * K + cs;
            pA[1][j] = Ab + ra1 * K + cs;
            pB[0][j] = Bb + rb0 * K + cs;
            pB[1][j] = Bb + rb1 * K + cs;
        }
    }

#define STAGE_A(H, KT) do { \
    _Pragma("unroll") \
    for (int j = 0; j < 2; ++j) \
        __builtin_amdgcn_global_load_lds((gas_ptr)(pA[H][j] + (long)(KT) * 64), \
            (las_ptr)(&L[(KT) & 1][0][H][0][0] + voff[j]), 16, 0, 0); \
} while (0)
#define STAGE_B(H, KT) do { \
    _Pragma("unroll") \
    for (int j = 0; j < 2; ++j) \
        __builtin_amdgcn_global_load_lds((gas_ptr)(pB[H][j] + (long)(KT) * 64), \
            (las_ptr)(&L[(KT) & 1][1][H][0][0] + voff[j]), 16, 0, 0); \
} while (0)

#define LOAD_AF(DST, CUR, QM) do { \
    _Pragma("unroll") \
    for (int m = 0; m < 4; ++m) \
        _Pragma("unroll") \
        for (int kk = 0; kk < 2; ++kk) \
            DST[m][kk] = *(const s16x8*)&L[CUR][0][QM][wm * 64 + m * 16 + lr][(kk * 32 + hi * 8) ^ sw]; \
} while (0)
#define LOAD_BQ(DST, CUR, QN) do { \
    _Pragma("unroll") \
    for (int n = 0; n < 2; ++n) \
        _Pragma("unroll") \
        for (int kk = 0; kk < 2; ++kk) \
            DST[n][kk] = *(const s16x8*)&L[CUR][1][QN][wn * 32 + n * 16 + lr][(kk * 32 + hi * 8) ^ sw]; \
} while (0)
#define MFMA_Q(QM, QN, AF, BQ) do { \
    _Pragma("unroll") \
    for (int m = 0; m < 4; ++m) \
        _Pragma("unroll") \
        for (int n = 0; n < 2; ++n) \
            _Pragma("unroll") \
            for (int kk = 0; kk < 2; ++kk) \
                acc[(QM) * 4 + m][(QN) * 2 + n] = __builtin_amdgcn_mfma_f32_16x16x32_bf16( \
                    AF[m][kk], BQ[n][kk], acc[(QM) * 4 + m][(QN) * 2 + n], 0, 0, 0); \
} while (0)

// One K-tile: 2 halves, 2 barriers. CUR = compile-time parity; BQ0 parity-owned.
#define TILE_BODY(CUR, KTE, BQ0) do { \
    const int kt_ = (KTE); \
    /* ---- H0 ---- */ \
    LOAD_AF(af0, CUR, 0); \
    LOAD_BQ(BQ0, CUR, 0); \
    LOAD_BQ(bq1, CUR, 1); \
    if (kt_ + 1 < nt) { STAGE_A(1, kt_ + 1); STAGE_B(1, kt_ + 1); } \
    __builtin_amdgcn_s_setprio(1); \
    MFMA_Q(0, 0, af0, BQ0); \
    MFMA_Q(0, 1, af0, bq1); \
    __builtin_amdgcn_s_setprio(0); \
    asm volatile("" ::: "memory"); \
    __builtin_amdgcn_s_barrier();   /* mid: H0 reads drained before H1 stages buf[cur] */ \
    asm volatile("" ::: "memory"); \
    /* ---- H1 ---- */ \
    LOAD_AF(af1, CUR, 1); \
    if (kt_ + 2 < nt) { STAGE_A(0, kt_ + 2); STAGE_B(0, kt_ + 2); } \
    __builtin_amdgcn_s_setprio(1); \
    MFMA_Q(1, 1, af1, bq1);   /* bq1 first: drained before its t+1 reload */ \
    MFMA_Q(1, 0, af1, BQ0); \
    __builtin_amdgcn_s_setprio(0); \
    /* ---- boundary: tile t+1 fully landed; keep A0B0(t+2) in flight ---- */ \
    if (kt_ + 1 < nt) { \
        if (kt_ + 2 < nt) asm volatile("s_waitcnt vmcnt(4)" ::: "memory"); \
        else              asm volatile("s_waitcnt vmcnt(0)" ::: "memory"); \
        __builtin_amdgcn_s_barrier(); \
        asm volatile("" ::: "memory"); \
    } \
} while (0)

    f32x4 acc[8][4];
    #pragma unroll
    for (int m = 0; m < 8; ++m)
        #pragma unroll
        for (int n = 0; n < 4; ++n)
            acc[m][n] = {0.f, 0.f, 0.f, 0.f};

    s16x8 af0[4][2], af1[4][2], bq0E[2][2], bq0O[2][2], bq1[2][2];

    // ---- prologue: tile0 all 4 halves + tile1 A0,B0; wait tile0 landed ----
    STAGE_A(0, 0); STAGE_B(0, 0); STAGE_A(1, 0); STAGE_B(1, 0);
    if (nt > 1) {
        STAGE_A(0, 1); STAGE_B(0, 1);
        asm volatile("s_waitcnt vmcnt(4)" ::: "memory");
    } else {
        asm volatile("s_waitcnt vmcnt(0)" ::: "memory");
    }
    __builtin_amdgcn_s_barrier();
    asm volatile("" ::: "memory");

    // nt is even for all shapes used here (K % 128 == 0).
    for (int kt = 0; kt < nt; kt += 2) {
        TILE_BODY(0, kt, bq0E);
        if (kt + 1 < nt) TILE_BODY(1, kt + 1, bq0O);
    }
#undef TILE_BODY
#undef STAGE_A
#undef STAGE_B
#undef LOAD_AF
#undef LOAD_BQ
#undef MFMA_Q

    // ---- epilogue: C[row][col], row = 16*am + hi*4 + i, col = 16*an + lr ----
    #pragma unroll
    for (int m = 0; m < 8; ++m) {
        #pragma unroll
        for (int n = 0; n < 4; ++n) {
            #pragma unroll
            for (int i = 0; i < 4; ++i) {
                long row = brow + wm * 128 + m * 16 + hi * 4 + i;
                long col = bcol + wn * 64 + n * 16 + lr;
                float vv = acc[m][n][i] * alpha;
                if constexpr (sizeof(CT) == 2) {
                    ((unsigned short*)C)[row * (long)N + col] = f2bf(vv);
                } else {
                    ((float*)C)[row * (long)N + col] = vv;
                }
            }
        }
    }
}

// ---------------- bf16 transpose: dst[c][r] = src[r][c], per-batch ----------------
__global__ __launch_bounds__(256) void transpose_bf16(const unsigned short* __restrict__ src,
                                                      unsigned short* __restrict__ dst,
                                                      int srows, int scols) {
    __shared__ unsigned short tile[64][66];
    const long bofs = (long)blockIdx.z * srows * scols;
    const unsigned short* s = src + bofs;
    unsigned short* d = dst + bofs;
    const int c0 = blockIdx.x * 64;
    const int r0 = blockIdx.y * 64;
    const int tx = threadIdx.x & 15;
    const int ty = threadIdx.x >> 4;

    #pragma unroll
    for (int k = 0; k < 4; ++k) {
        int r = ty + 16 * k;
        ushort4 v = *(const ushort4*)(s + (long)(r0 + r) * scols + c0 + tx * 4);
        tile[r][tx * 4 + 0] = v.x; tile[r][tx * 4 + 1] = v.y;
        tile[r][tx * 4 + 2] = v.z; tile[r][tx * 4 + 3] = v.w;
    }
    __syncthreads();
    #pragma unroll
    for (int k = 0; k < 4; ++k) {
        int dr = ty + 16 * k;
        ushort4 v;
        v.x = tile[tx * 4 + 0][dr]; v.y = tile[tx * 4 + 1][dr];
        v.z = tile[tx * 4 + 2][dr]; v.w = tile[tx * 4 + 3][dr];
        *(ushort4*)(d + (long)(c0 + dr) * srows + r0 + tx * 4) = v;
    }
}

// ---------------- row softmax, in place, bf16, ncols = 4096 ----------------
__global__ __launch_bounds__(256) void softmax_inplace(unsigned short* __restrict__ S, int ncols) {
    const long row = blockIdx.x;
    unsigned short* p = S + row * (long)ncols;
    const int t = threadIdx.x;
    const int wid = t >> 6;

    ushort4 raw[4];
    const ushort4* pv = (const ushort4*)(p + t * 16);
    #pragma unroll
    for (int i = 0; i < 4; ++i) raw[i] = pv[i];

    float v[16];
    float mx = -1e30f;
    #pragma unroll
    for (int i = 0; i < 4; ++i) {
        v[4*i+0] = bf2f(raw[i].x); v[4*i+1] = bf2f(raw[i].y);
        v[4*i+2] = bf2f(raw[i].z); v[4*i+3] = bf2f(raw[i].w);
    }
    #pragma unroll
    for (int i = 0; i < 16; ++i) mx = fmaxf(mx, v[i]);
    #pragma unroll
    for (int off = 32; off > 0; off >>= 1) mx = fmaxf(mx, __shfl_xor(mx, off));

    __shared__ float red[8];
    if ((t & 63) == 0) red[wid] = mx;
    __syncthreads();
    mx = fmaxf(fmaxf(red[0], red[1]), fmaxf(red[2], red[3]));

    float sum = 0.f;
    #pragma unroll
    for (int i = 0; i < 16; ++i) { v[i] = __expf(v[i] - mx); sum += v[i]; }
    #pragma unroll
    for (int off = 32; off > 0; off >>= 1) sum += __shfl_xor(sum, off);
    __syncthreads();
    if ((t & 63) == 0) red[4 + wid] = sum;
    __syncthreads();
    sum = red[4] + red[5] + red[6] + red[7];
    const float inv = 1.0f / sum;

    ushort4* po = (ushort4*)(p + t * 16);
    #pragma unroll
    for (int i = 0; i < 4; ++i) {
        ushort4 o;
        o.x = f2bf(v[4*i+0] * inv); o.y = f2bf(v[4*i+1] * inv);
        o.z = f2bf(v[4*i+2] * inv); o.w = f2bf(v[4*i+3] * inv);
        po[i] = o;
    }
}

extern "C" void kernel_launch(void* const* d_in, const int* in_sizes, int n_in,
                              void* d_out, int out_size, void* d_ws, size_t ws_size,
                              hipStream_t stream) {
    const float* x  = (const float*)d_in[0];
    const float* wq = (const float*)d_in[1];
    const float* wk = (const float*)d_in[2];
    const float* wv = (const float*)d_in[3];
    const float* wo = (const float*)d_in[4];
    float* out = (float*)d_out;

    const long SDIM = 2048, SEQ = 4096, BATCH = 2;
    const long MS = BATCH * SEQ;       // 8192
    const long XN = MS * SDIM;         // 16,777,216
    const long WN = SDIM * SDIM;       // 4,194,304

    unsigned short* ws  = (unsigned short*)d_ws;
    unsigned short* Xbf = ws;               // XN elems (reused as Vt later)
    unsigned short* Wqb = ws + XN;
    unsigned short* Wkb = Wqb + WN;
    unsigned short* Wvb = Wkb + WN;
    unsigned short* Wob = Wvb + WN;
    unsigned short* Qb  = Wob + WN;         // XN (reused as Ctx later)
    unsigned short* Kb  = Qb + XN;
    unsigned short* Vb  = Kb + XN;
    unsigned short* Sb  = Vb + XN;          // 2*4096*4096 bf16
    unsigned short* Vt  = Xbf;
    unsigned short* Ctx = Qb;

    // fp32 -> bf16 conversions
    cvt_f32_bf16<<<(int)(XN / 2048), 256, 0, stream>>>(x,  Xbf, XN);
    cvt_f32_bf16<<<(int)(WN / 2048), 256, 0, stream>>>(wq, Wqb, WN);
    cvt_f32_bf16<<<(int)(WN / 2048), 256, 0, stream>>>(wk, Wkb, WN);
    cvt_f32_bf16<<<(int)(WN / 2048), 256, 0, stream>>>(wv, Wvb, WN);
    cvt_f32_bf16<<<(int)(WN / 2048), 256, 0, stream>>>(wo, Wob, WN);

    // projections: [8192,2048] = Xbf @ W^T
    dim3 gp((unsigned)(MS / 256), (unsigned)(SDIM / 256), 1);
    gemm256_bt<unsigned short><<<gp, 512, 0, stream>>>(Xbf, Wqb, Qb, (int)SDIM, (int)SDIM, (int)(SDIM / 64), 0, 0, 0, 1.0f);
    gemm256_bt<unsigned short><<<gp, 512, 0, stream>>>(Xbf, Wkb, Kb, (int)SDIM, (int)SDIM, (int)(SDIM / 64), 0, 0, 0, 1.0f);
    gemm256_bt<unsigned short><<<gp, 512, 0, stream>>>(Xbf, Wvb, Vb, (int)SDIM, (int)SDIM, (int)(SDIM / 64), 0, 0, 0, 1.0f);

    // V -> V^T per batch (Vt overwrites Xbf region; X no longer needed)
    dim3 gt((unsigned)(SDIM / 64), (unsigned)(SEQ / 64), (unsigned)BATCH);
    transpose_bf16<<<gt, 256, 0, stream>>>(Vb, Vt, (int)SEQ, (int)SDIM);

    // scores: S[b] = Q[b] @ K[b]^T * (1/sqrt(D))
    const float scale = 1.0f / sqrtf((float)SDIM);
    dim3 gs((unsigned)(SEQ / 256), (unsigned)(SEQ / 256), (unsigned)BATCH);
    gemm256_bt<unsigned short><<<gs, 512, 0, stream>>>(Qb, Kb, Sb, (int)SEQ, (int)SDIM, (int)(SDIM / 64),
                                                       SEQ * SDIM, SEQ * SDIM, SEQ * SEQ, scale);

    // softmax rows in place
    softmax_inplace<<<(int)(BATCH * SEQ), 256, 0, stream>>>(Sb, (int)SEQ);

    // ctx[b] = P[b] @ Vt[b]^T : M=SEQ, N=SDIM, K=SEQ  (Ctx overwrites Qb)
    dim3 gc((unsigned)(SEQ / 256), (unsigned)(SDIM / 256), (unsigned)BATCH);
    gemm256_bt<unsigned short><<<gc, 512, 0, stream>>>(Sb, Vt, Ctx, (int)SDIM, (int)SEQ, (int)(SEQ / 64),
                                                       SEQ * SEQ, SDIM * SEQ, SEQ * SDIM, 1.0f);

    // out = Ctx @ Wo^T  (fp32 out, flat [8192,2048])
    gemm256_bt<float><<<gp, 512, 0, stream>>>(Ctx, Wob, out, (int)SDIM, (int)SDIM, (int)(SDIM / 64), 0, 0, 0, 1.0f);
}

// Round 9
// 550.500 us; speedup vs baseline: 1.5403x; 1.0001x over previous
//
#include <hip/hip_runtime.h>
#include <hip/hip_bf16.h>
#include <stdint.h>
#include <math.h>

typedef __attribute__((ext_vector_type(4))) float f32x4;
typedef __attribute__((ext_vector_type(8))) short s16x8;

typedef const __attribute__((address_space(1))) void* gas_ptr;
typedef __attribute__((address_space(3))) void* las_ptr;

__device__ __forceinline__ float bf2f(unsigned short u) {
    union { unsigned int i; float f; } x; x.i = ((unsigned int)u) << 16; return x.f;
}
__device__ __forceinline__ unsigned short f2bf(float f) {
    union { float f; unsigned int u; } x; x.f = f;
    unsigned int r = x.u + 0x7FFFu + ((x.u >> 16) & 1u);
    return (unsigned short)(r >> 16);
}

// ---------------- fp32 -> bf16 ----------------
__global__ __launch_bounds__(256) void cvt_f32_bf16(const float* __restrict__ src,
                                                    unsigned short* __restrict__ dst,
                                                    long n) {
    long i = ((long)blockIdx.x * 256 + threadIdx.x) * 8;
    if (i + 8 > n) return;
    f32x4 a = *(const f32x4*)(src + i);
    f32x4 b = *(const f32x4*)(src + i + 4);
    s16x8 o;
    o[0] = (short)f2bf(a[0]); o[1] = (short)f2bf(a[1]);
    o[2] = (short)f2bf(a[2]); o[3] = (short)f2bf(a[3]);
    o[4] = (short)f2bf(b[0]); o[5] = (short)f2bf(b[1]);
    o[6] = (short)f2bf(b[2]); o[7] = (short)f2bf(b[3]);
    *(s16x8*)(dst + i) = o;
}

// ============ 256x256 bf16 GEMM, ONE barrier per K-tile ============
// r8 (2 barriers/K-tile) -> r9 (1 barrier/K-tile): all staging during tile t
// targets buf^1 (tile t+1) and issues in H0, so no stage ever touches a
// region read this tile -> the mid-barrier is gone. Waves free-run across the
// whole K-tile (one wave's ds_read burst overlaps the other's MFMA drain on
// each SIMD, m114 mechanism), syncing once per tile.
//   H0: read af0,bq0,bq1 (16) | stage ALL of t+1 -> buf^1 (8 glds) |
//       MFMA (0,0),(0,1)
//   H1: read af1 (8) | MFMA (1,1),(1,0)
//   boundary: vmcnt(0) + barrier. Issue-to-wait distance ~1300+ cyc > HBM
//       latency ~900 -> the drain is free (m233's stall needs SHORT distance).
// Hazards: af1(t) staged in t-1's H0, gated by t-1's boundary ✓; staged
// regions' last readers completed before previous boundary (lgkm waits precede
// MFMA issue precede barrier arrival) ✓; bq0 WAR across the barrier handled by
// parity-doubling (bq0E/bq0O) ✓. No manual lgkmcnt (compiler emits minimal
// counted waits). Swizzle (T2): col ^= ((row&7)<<3), pre-swizzled global src +
// same XOR on read. T1: XCD-aware blockIdx.x swizzle (gridDim.x % 8 == 0).
template <typename CT>
__global__ __launch_bounds__(512, 2)
void gemm256_bt(const unsigned short* __restrict__ A,
                const unsigned short* __restrict__ B,
                CT* __restrict__ C,
                int N, int K, int nt,
                long sA, long sB, long sC, float alpha)
{
    A += (long)blockIdx.z * sA;
    B += (long)blockIdx.z * sB;
    C += (long)blockIdx.z * sC;

    __shared__ unsigned short L[2][2][2][128][64];   // 128 KiB

    const int t    = threadIdx.x;
    const int lane = t & 63;
    const int wid  = t >> 6;        // 0..7
    const int wm   = wid >> 2;      // 0..1
    const int wn   = wid & 3;       // 0..3

    // T1: XCD swizzle on x (M-tiles): XCD k gets a contiguous chunk of rows.
    const int cpx = (int)gridDim.x >> 3;
    const int bx  = ((int)blockIdx.x & 7) * cpx + ((int)blockIdx.x >> 3);
    const long brow = (long)bx * 256;
    const long bcol = (long)blockIdx.y * 256;

    const int lr = lane & 15;
    const int hi = lane >> 4;            // 0..3
    const int sw = (lr & 7) << 3;        // ds_read swizzle (element units)

    // ---- staging precompute: thread t, chunk j handles linear u = t + 512j ----
    int voff[2];                      // LDS element offset u*8
    const unsigned short* pA[2][2];   // [sub][j] global src (pre-swizzled), k0=0
    const unsigned short* pB[2][2];
    {
        const unsigned short* Ab = A + brow * K;
        const unsigned short* Bb = B + bcol * K;
        #pragma unroll
        for (int j = 0; j < 2; ++j) {
            int u  = t + 512 * j;
            int ix = u >> 3;                       // phys row in [128][64] region
            int cg = u & 7;
            int cs = (cg * 8) ^ ((ix & 7) << 3);   // pre-swizzled col
            voff[j] = u * 8;
            long ra0 = ((long)(ix >> 6) << 7) | (0 << 6) | (ix & 63);
            long ra1 = ((long)(ix >> 6) << 7) | (1 << 6) | (ix & 63);
            long rb0 = ((long)(ix >> 5) << 6) | (0 << 5) | (ix & 31);
            long rb1 = ((long)(ix >> 5) << 6) | (1 << 5) | (ix & 31);
            pA[0][j] = Ab + ra0 * K + cs;
            pA[1][j] = Ab + ra1 * K + cs;
            pB[0][j] = Bb + rb0 * K + cs;
            pB[1][j] = Bb + rb1 * K + cs;
        }
    }

#define STAGE_A(H, KT) do { \
    _Pragma("unroll") \
    for (int j = 0; j < 2; ++j) \
        __builtin_amdgcn_global_load_lds((gas_ptr)(pA[H][j] + (long)(KT) * 64), \
            (las_ptr)(&L[(KT) & 1][0][H][0][0] + voff[j]), 16, 0, 0); \
} while (0)
#define STAGE_B(H, KT) do { \
    _Pragma("unroll") \
    for (int j = 0; j < 2; ++j) \
        __builtin_amdgcn_global_load_lds((gas_ptr)(pB[H][j] + (long)(KT) * 64), \
            (las_ptr)(&L[(KT) & 1][1][H][0][0] + voff[j]), 16, 0, 0); \
} while (0)

#define LOAD_AF(DST, CUR, QM) do { \
    _Pragma("unroll") \
    for (int m = 0; m < 4; ++m) \
        _Pragma("unroll") \
        for (int kk = 0; kk < 2; ++kk) \
            DST[m][kk] = *(const s16x8*)&L[CUR][0][QM][wm * 64 + m * 16 + lr][(kk * 32 + hi * 8) ^ sw]; \
} while (0)
#define LOAD_BQ(DST, CUR, QN) do { \
    _Pragma("unroll") \
    for (int n = 0; n < 2; ++n) \
        _Pragma("unroll") \
        for (int kk = 0; kk < 2; ++kk) \
            DST[n][kk] = *(const s16x8*)&L[CUR][1][QN][wn * 32 + n * 16 + lr][(kk * 32 + hi * 8) ^ sw]; \
} while (0)
#define MFMA_Q(QM, QN, AF, BQ) do { \
    _Pragma("unroll") \
    for (int m = 0; m < 4; ++m) \
        _Pragma("unroll") \
        for (int n = 0; n < 2; ++n) \
            _Pragma("unroll") \
            for (int kk = 0; kk < 2; ++kk) \
                acc[(QM) * 4 + m][(QN) * 2 + n] = __builtin_amdgcn_mfma_f32_16x16x32_bf16( \
                    AF[m][kk], BQ[n][kk], acc[(QM) * 4 + m][(QN) * 2 + n], 0, 0, 0); \
} while (0)

// One K-tile: 1 barrier. CUR = compile-time parity; BQ0 parity-owned set.
#define TILE_BODY(CUR, KTE, BQ0) do { \
    const int kt_ = (KTE); \
    /* ---- H0: reads, full next-tile stage (buf^1, race-free), 32 MFMA ---- */ \
    LOAD_AF(af0, CUR, 0); \
    LOAD_BQ(BQ0, CUR, 0); \
    LOAD_BQ(bq1, CUR, 1); \
    if (kt_ + 1 < nt) { \
        STAGE_A(0, kt_ + 1); STAGE_B(0, kt_ + 1); \
        STAGE_A(1, kt_ + 1); STAGE_B(1, kt_ + 1); \
    } \
    __builtin_amdgcn_s_setprio(1); \
    MFMA_Q(0, 0, af0, BQ0); \
    MFMA_Q(0, 1, af0, bq1); \
    __builtin_amdgcn_s_setprio(0); \
    /* ---- H1: A1 reads, 32 MFMA ---- */ \
    LOAD_AF(af1, CUR, 1); \
    __builtin_amdgcn_s_setprio(1); \
    MFMA_Q(1, 1, af1, bq1); \
    MFMA_Q(1, 0, af1, BQ0); \
    __builtin_amdgcn_s_setprio(0); \
    /* ---- boundary: t+1 fully landed (issued ~1300cy ago, no stall) ---- */ \
    if (kt_ + 1 < nt) { \
        asm volatile("s_waitcnt vmcnt(0)" ::: "memory"); \
        __builtin_amdgcn_s_barrier(); \
        asm volatile("" ::: "memory"); \
    } \
} while (0)

    f32x4 acc[8][4];
    #pragma unroll
    for (int m = 0; m < 8; ++m)
        #pragma unroll
        for (int n = 0; n < 4; ++n)
            acc[m][n] = {0.f, 0.f, 0.f, 0.f};

    s16x8 af0[4][2], af1[4][2], bq0E[2][2], bq0O[2][2], bq1[2][2];

    // ---- prologue: stage tile 0, drain, barrier ----
    STAGE_A(0, 0); STAGE_B(0, 0); STAGE_A(1, 0); STAGE_B(1, 0);
    asm volatile("s_waitcnt vmcnt(0)" ::: "memory");
    __builtin_amdgcn_s_barrier();
    asm volatile("" ::: "memory");

    // nt is even for all shapes used here (K % 128 == 0).
    for (int kt = 0; kt < nt; kt += 2) {
        TILE_BODY(0, kt, bq0E);
        if (kt + 1 < nt) TILE_BODY(1, kt + 1, bq0O);
    }
#undef TILE_BODY
#undef STAGE_A
#undef STAGE_B
#undef LOAD_AF
#undef LOAD_BQ
#undef MFMA_Q

    // ---- epilogue: C[row][col], row = 16*am + hi*4 + i, col = 16*an + lr ----
    #pragma unroll
    for (int m = 0; m < 8; ++m) {
        #pragma unroll
        for (int n = 0; n < 4; ++n) {
            #pragma unroll
            for (int i = 0; i < 4; ++i) {
                long row = brow + wm * 128 + m * 16 + hi * 4 + i;
                long col = bcol + wn * 64 + n * 16 + lr;
                float vv = acc[m][n][i] * alpha;
                if constexpr (sizeof(CT) == 2) {
                    ((unsigned short*)C)[row * (long)N + col] = f2bf(vv);
                } else {
                    ((float*)C)[row * (long)N + col] = vv;
                }
            }
        }
    }
}

// ---------------- bf16 transpose: dst[c][r] = src[r][c], per-batch ----------------
__global__ __launch_bounds__(256) void transpose_bf16(const unsigned short* __restrict__ src,
                                                      unsigned short* __restrict__ dst,
                                                      int srows, int scols) {
    __shared__ unsigned short tile[64][66];
    const long bofs = (long)blockIdx.z * srows * scols;
    const unsigned short* s = src + bofs;
    unsigned short* d = dst + bofs;
    const int c0 = blockIdx.x * 64;
    const int r0 = blockIdx.y * 64;
    const int tx = threadIdx.x & 15;
    const int ty = threadIdx.x >> 4;

    #pragma unroll
    for (int k = 0; k < 4; ++k) {
        int r = ty + 16 * k;
        ushort4 v = *(const ushort4*)(s + (long)(r0 + r) * scols + c0 + tx * 4);
        tile[r][tx * 4 + 0] = v.x; tile[r][tx * 4 + 1] = v.y;
        tile[r][tx * 4 + 2] = v.z; tile[r][tx * 4 + 3] = v.w;
    }
    __syncthreads();
    #pragma unroll
    for (int k = 0; k < 4; ++k) {
        int dr = ty + 16 * k;
        ushort4 v;
        v.x = tile[tx * 4 + 0][dr]; v.y = tile[tx * 4 + 1][dr];
        v.z = tile[tx * 4 + 2][dr]; v.w = tile[tx * 4 + 3][dr];
        *(ushort4*)(d + (long)(c0 + dr) * srows + r0 + tx * 4) = v;
    }
}

// ---------------- row softmax, in place, bf16, ncols = 4096 ----------------
__global__ __launch_bounds__(256) void softmax_inplace(unsigned short* __restrict__ S, int ncols) {
    const long row = blockIdx.x;
    unsigned short* p = S + row * (long)ncols;
    const int t = threadIdx.x;
    const int wid = t >> 6;

    ushort4 raw[4];
    const ushort4* pv = (const ushort4*)(p + t * 16);
    #pragma unroll
    for (int i = 0; i < 4; ++i) raw[i] = pv[i];

    float v[16];
    float mx = -1e30f;
    #pragma unroll
    for (int i = 0; i < 4; ++i) {
        v[4*i+0] = bf2f(raw[i].x); v[4*i+1] = bf2f(raw[i].y);
        v[4*i+2] = bf2f(raw[i].z); v[4*i+3] = bf2f(raw[i].w);
    }
    #pragma unroll
    for (int i = 0; i < 16; ++i) mx = fmaxf(mx, v[i]);
    #pragma unroll
    for (int off = 32; off > 0; off >>= 1) mx = fmaxf(mx, __shfl_xor(mx, off));

    __shared__ float red[8];
    if ((t & 63) == 0) red[wid] = mx;
    __syncthreads();
    mx = fmaxf(fmaxf(red[0], red[1]), fmaxf(red[2], red[3]));

    float sum = 0.f;
    #pragma unroll
    for (int i = 0; i < 16; ++i) { v[i] = __expf(v[i] - mx); sum += v[i]; }
    #pragma unroll
    for (int off = 32; off > 0; off >>= 1) sum += __shfl_xor(sum, off);
    __syncthreads();
    if ((t & 63) == 0) red[4 + wid] = sum;
    __syncthreads();
    sum = red[4] + red[5] + red[6] + red[7];
    const float inv = 1.0f / sum;

    ushort4* po = (ushort4*)(p + t * 16);
    #pragma unroll
    for (int i = 0; i < 4; ++i) {
        ushort4 o;
        o.x = f2bf(v[4*i+0] * inv); o.y = f2bf(v[4*i+1] * inv);
        o.z = f2bf(v[4*i+2] * inv); o.w = f2bf(v[4*i+3] * inv);
        po[i] = o;
    }
}

extern "C" void kernel_launch(void* const* d_in, const int* in_sizes, int n_in,
                              void* d_out, int out_size, void* d_ws, size_t ws_size,
                              hipStream_t stream) {
    const float* x  = (const float*)d_in[0];
    const float* wq = (const float*)d_in[1];
    const float* wk = (const float*)d_in[2];
    const float* wv = (const float*)d_in[3];
    const float* wo = (const float*)d_in[4];
    float* out = (float*)d_out;

    const long SDIM = 2048, SEQ = 4096, BATCH = 2;
    const long MS = BATCH * SEQ;       // 8192
    const long XN = MS * SDIM;         // 16,777,216
    const long WN = SDIM * SDIM;       // 4,194,304

    unsigned short* ws  = (unsigned short*)d_ws;
    unsigned short* Xbf = ws;               // XN elems (reused as Vt later)
    unsigned short* Wqb = ws + XN;
    unsigned short* Wkb = Wqb + WN;
    unsigned short* Wvb = Wkb + WN;
    unsigned short* Wob = Wvb + WN;
    unsigned short* Qb  = Wob + WN;         // XN (reused as Ctx later)
    unsigned short* Kb  = Qb + XN;
    unsigned short* Vb  = Kb + XN;
    unsigned short* Sb  = Vb + XN;          // 2*4096*4096 bf16
    unsigned short* Vt  = Xbf;
    unsigned short* Ctx = Qb;

    // fp32 -> bf16 conversions
    cvt_f32_bf16<<<(int)(XN / 2048), 256, 0, stream>>>(x,  Xbf, XN);
    cvt_f32_bf16<<<(int)(WN / 2048), 256, 0, stream>>>(wq, Wqb, WN);
    cvt_f32_bf16<<<(int)(WN / 2048), 256, 0, stream>>>(wk, Wkb, WN);
    cvt_f32_bf16<<<(int)(WN / 2048), 256, 0, stream>>>(wv, Wvb, WN);
    cvt_f32_bf16<<<(int)(WN / 2048), 256, 0, stream>>>(wo, Wob, WN);

    // projections: [8192,2048] = Xbf @ W^T
    dim3 gp((unsigned)(MS / 256), (unsigned)(SDIM / 256), 1);
    gemm256_bt<unsigned short><<<gp, 512, 0, stream>>>(Xbf, Wqb, Qb, (int)SDIM, (int)SDIM, (int)(SDIM / 64), 0, 0, 0, 1.0f);
    gemm256_bt<unsigned short><<<gp, 512, 0, stream>>>(Xbf, Wkb, Kb, (int)SDIM, (int)SDIM, (int)(SDIM / 64), 0, 0, 0, 1.0f);
    gemm256_bt<unsigned short><<<gp, 512, 0, stream>>>(Xbf, Wvb, Vb, (int)SDIM, (int)SDIM, (int)(SDIM / 64), 0, 0, 0, 1.0f);

    // V -> V^T per batch (Vt overwrites Xbf region; X no longer needed)
    dim3 gt((unsigned)(SDIM / 64), (unsigned)(SEQ / 64), (unsigned)BATCH);
    transpose_bf16<<<gt, 256, 0, stream>>>(Vb, Vt, (int)SEQ, (int)SDIM);

    // scores: S[b] = Q[b] @ K[b]^T * (1/sqrt(D))
    const float scale = 1.0f / sqrtf((float)SDIM);
    dim3 gs((unsigned)(SEQ / 256), (unsigned)(SEQ / 256), (unsigned)BATCH);
    gemm256_bt<unsigned short><<<gs, 512, 0, stream>>>(Qb, Kb, Sb, (int)SEQ, (int)SDIM, (int)(SDIM / 64),
                                                       SEQ * SDIM, SEQ * SDIM, SEQ * SEQ, scale);

    // softmax rows in place
    softmax_inplace<<<(int)(BATCH * SEQ), 256, 0, stream>>>(Sb, (int)SEQ);

    // ctx[b] = P[b] @ Vt[b]^T : M=SEQ, N=SDIM, K=SEQ  (Ctx overwrites Qb)
    dim3 gc((unsigned)(SEQ / 256), (unsigned)(SDIM / 256), (unsigned)BATCH);
    gemm256_bt<unsigned short><<<gc, 512, 0, stream>>>(Sb, Vt, Ctx, (int)SDIM, (int)SEQ, (int)(SEQ / 64),
                                                       SEQ * SEQ, SDIM * SEQ, SEQ * SDIM, 1.0f);

    // out = Ctx @ Wo^T  (fp32 out, flat [8192,2048])
    gemm256_bt<float><<<gp, 512, 0, stream>>>(Ctx, Wob, out, (int)SDIM, (int)SDIM, (int)(SDIM / 64), 0, 0, 0, 1.0f);
}

// Round 10
// 538.146 us; speedup vs baseline: 1.5757x; 1.0230x over previous
//
#include <hip/hip_runtime.h>
#include <hip/hip_bf16.h>
#include <stdint.h>
#include <math.h>

typedef __attribute__((ext_vector_type(4))) float f32x4;
typedef __attribute__((ext_vector_type(8))) short s16x8;

typedef const __attribute__((address_space(1))) void* gas_ptr;
typedef __attribute__((address_space(3))) void* las_ptr;

__device__ __forceinline__ float bf2f(unsigned short u) {
    union { unsigned int i; float f; } x; x.i = ((unsigned int)u) << 16; return x.f;
}
__device__ __forceinline__ unsigned short f2bf(float f) {
    union { float f; unsigned int u; } x; x.f = f;
    unsigned int r = x.u + 0x7FFFu + ((x.u >> 16) & 1u);
    return (unsigned short)(r >> 16);
}

// ---------------- fp32 -> bf16 ----------------
__global__ __launch_bounds__(256) void cvt_f32_bf16(const float* __restrict__ src,
                                                    unsigned short* __restrict__ dst,
                                                    long n) {
    long i = ((long)blockIdx.x * 256 + threadIdx.x) * 8;
    if (i + 8 > n) return;
    f32x4 a = *(const f32x4*)(src + i);
    f32x4 b = *(const f32x4*)(src + i + 4);
    s16x8 o;
    o[0] = (short)f2bf(a[0]); o[1] = (short)f2bf(a[1]);
    o[2] = (short)f2bf(a[2]); o[3] = (short)f2bf(a[3]);
    o[4] = (short)f2bf(b[0]); o[5] = (short)f2bf(b[1]);
    o[6] = (short)f2bf(b[2]); o[7] = (short)f2bf(b[3]);
    *(s16x8*)(dst + i) = o;
}

// ============ 256x256 bf16 GEMM, cross-barrier software pipeline ============
// r9 diagnosis: 1 block/CU (128KB LDS), 2 waves/SIMD; the boundary barrier
// phase-aligns all 8 waves, so each tile starts with a ~1200-1500cy window
// where ALL waves burst ds_reads and the matrix pipe idles (then vice versa).
// r10: hold tile t's H1 MFMA cluster (operands in REGISTERS: af1,bq0,bq1)
// and issue it first thing AFTER the boundary barrier -- it feeds the matrix
// pipe during tile t+1's read burst. Per-tile body:
//   MFMA H1(t-1) [pure reg]  ||  LOAD af0,bq0,bq1(t)  ||  STAGE(t+1)->buf^1
//   MFMA H0(t)
//   LOAD af1(t)              [consumed post-barrier in t+1]
//   lgkmcnt(0)   <- af1(t) reads have NO pre-barrier consumer; must drain own
//                   ds_reads before barrier else STAGE by another wave races
//   vmcnt(0); barrier
// Register WAR (bq0/bq1/af1 reloaded right after the MFMAs that read them) is
// program-order safe -> no parity doubling. No sched pins (r4/m141 lesson);
// compiler interleaves the independent H1-MFMA and read streams.
// Swizzle (T2): col ^= ((row&7)<<3), pre-swizzled global src + same XOR on
// ds_read. T1: XCD-aware blockIdx.x swizzle (gridDim.x % 8 == 0).
template <typename CT>
__global__ __launch_bounds__(512, 2)
void gemm256_bt(const unsigned short* __restrict__ A,
                const unsigned short* __restrict__ B,
                CT* __restrict__ C,
                int N, int K, int nt,
                long sA, long sB, long sC, float alpha)
{
    A += (long)blockIdx.z * sA;
    B += (long)blockIdx.z * sB;
    C += (long)blockIdx.z * sC;

    __shared__ unsigned short L[2][2][2][128][64];   // 128 KiB

    const int t    = threadIdx.x;
    const int lane = t & 63;
    const int wid  = t >> 6;        // 0..7
    const int wm   = wid >> 2;      // 0..1
    const int wn   = wid & 3;       // 0..3

    // T1: XCD swizzle on x (M-tiles): XCD k gets a contiguous chunk of rows.
    const int cpx = (int)gridDim.x >> 3;
    const int bx  = ((int)blockIdx.x & 7) * cpx + ((int)blockIdx.x >> 3);
    const long brow = (long)bx * 256;
    const long bcol = (long)blockIdx.y * 256;

    const int lr = lane & 15;
    const int hi = lane >> 4;            // 0..3
    const int sw = (lr & 7) << 3;        // ds_read swizzle (element units)

    // ---- staging precompute: thread t, chunk j handles linear u = t + 512j ----
    int voff[2];                      // LDS element offset u*8
    const unsigned short* pA[2][2];   // [sub][j] global src (pre-swizzled), k0=0
    const unsigned short* pB[2][2];
    {
        const unsigned short* Ab = A + brow * K;
        const unsigned short* Bb = B + bcol * K;
        #pragma unroll
        for (int j = 0; j < 2; ++j) {
            int u  = t + 512 * j;
            int ix = u >> 3;                       // phys row in [128][64] region
            int cg = u & 7;
            int cs = (cg * 8) ^ ((ix & 7) << 3);   // pre-swizzled col
            voff[j] = u * 8;
            long ra0 = ((long)(ix >> 6) << 7) | (0 << 6) | (ix & 63);
            long ra1 = ((long)(ix >> 6) << 7) | (1 << 6) | (ix & 63);
            long rb0 = ((long)(ix >> 5) << 6) | (0 << 5) | (ix & 31);
            long rb1 = ((long)(ix >> 5) << 6) | (1 << 5) | (ix & 31);
            pA[0][j] = Ab + ra0 * K + cs;
            pA[1][j] = Ab + ra1 * K + cs;
            pB[0][j] = Bb + rb0 * K + cs;
            pB[1][j] = Bb + rb1 * K + cs;
        }
    }

#define STAGE_A(H, KT) do { \
    _Pragma("unroll") \
    for (int j = 0; j < 2; ++j) \
        __builtin_amdgcn_global_load_lds((gas_ptr)(pA[H][j] + (long)(KT) * 64), \
            (las_ptr)(&L[(KT) & 1][0][H][0][0] + voff[j]), 16, 0, 0); \
} while (0)
#define STAGE_B(H, KT) do { \
    _Pragma("unroll") \
    for (int j = 0; j < 2; ++j) \
        __builtin_amdgcn_global_load_lds((gas_ptr)(pB[H][j] + (long)(KT) * 64), \
            (las_ptr)(&L[(KT) & 1][1][H][0][0] + voff[j]), 16, 0, 0); \
} while (0)

#define LOAD_AF(DST, CUR, QM) do { \
    _Pragma("unroll") \
    for (int m = 0; m < 4; ++m) \
        _Pragma("unroll") \
        for (int kk = 0; kk < 2; ++kk) \
            DST[m][kk] = *(const s16x8*)&L[CUR][0][QM][wm * 64 + m * 16 + lr][(kk * 32 + hi * 8) ^ sw]; \
} while (0)
#define LOAD_BQ(DST, CUR, QN) do { \
    _Pragma("unroll") \
    for (int n = 0; n < 2; ++n) \
        _Pragma("unroll") \
        for (int kk = 0; kk < 2; ++kk) \
            DST[n][kk] = *(const s16x8*)&L[CUR][1][QN][wn * 32 + n * 16 + lr][(kk * 32 + hi * 8) ^ sw]; \
} while (0)
#define MFMA_Q(QM, QN, AF, BQ) do { \
    _Pragma("unroll") \
    for (int m = 0; m < 4; ++m) \
        _Pragma("unroll") \
        for (int n = 0; n < 2; ++n) \
            _Pragma("unroll") \
            for (int kk = 0; kk < 2; ++kk) \
                acc[(QM) * 4 + m][(QN) * 2 + n] = __builtin_amdgcn_mfma_f32_16x16x32_bf16( \
                    AF[m][kk], BQ[n][kk], acc[(QM) * 4 + m][(QN) * 2 + n], 0, 0, 0); \
} while (0)

    f32x4 acc[8][4];
    #pragma unroll
    for (int m = 0; m < 8; ++m)
        #pragma unroll
        for (int n = 0; n < 4; ++n)
            acc[m][n] = {0.f, 0.f, 0.f, 0.f};

    s16x8 af0[4][2], af1[4][2], bq0[2][2], bq1[2][2];

    // ---- prologue: stage tile 0, drain, barrier ----
    STAGE_A(0, 0); STAGE_B(0, 0); STAGE_A(1, 0); STAGE_B(1, 0);
    asm volatile("s_waitcnt vmcnt(0)" ::: "memory");
    __builtin_amdgcn_s_barrier();
    asm volatile("" ::: "memory");

    // ---- tile 0 (no held H1 yet) ----
    LOAD_AF(af0, 0, 0);
    LOAD_BQ(bq0, 0, 0);
    LOAD_BQ(bq1, 0, 1);
    if (nt > 1) {
        STAGE_A(0, 1); STAGE_B(0, 1);
        STAGE_A(1, 1); STAGE_B(1, 1);
    }
    __builtin_amdgcn_s_setprio(1);
    MFMA_Q(0, 0, af0, bq0);
    MFMA_Q(0, 1, af0, bq1);
    __builtin_amdgcn_s_setprio(0);
    LOAD_AF(af1, 0, 1);
    asm volatile("s_waitcnt lgkmcnt(0)" ::: "memory");
    asm volatile("s_waitcnt vmcnt(0)" ::: "memory");
    __builtin_amdgcn_s_barrier();
    asm volatile("" ::: "memory");

    // ---- steady state: H1(kt-1) fills the matrix pipe during kt's read burst ----
    for (int kt = 1; kt < nt; ++kt) {
        const int cur = kt & 1;
        // H1 of previous tile: pure-register MFMA, overlaps this tile's reads
        __builtin_amdgcn_s_setprio(1);
        MFMA_Q(1, 1, af1, bq1);
        MFMA_Q(1, 0, af1, bq0);
        __builtin_amdgcn_s_setprio(0);
        // reads for tile kt (WAR on bq0/bq1/af1 vs above MFMAs: program order)
        LOAD_AF(af0, cur, 0);
        LOAD_BQ(bq0, cur, 0);
        LOAD_BQ(bq1, cur, 1);
        if (kt + 1 < nt) {
            STAGE_A(0, kt + 1); STAGE_B(0, kt + 1);
            STAGE_A(1, kt + 1); STAGE_B(1, kt + 1);
        }
        __builtin_amdgcn_s_setprio(1);
        MFMA_Q(0, 0, af0, bq0);
        MFMA_Q(0, 1, af0, bq1);
        __builtin_amdgcn_s_setprio(0);
        LOAD_AF(af1, cur, 1);
        // own ds_reads must drain before barrier (af1 has no pre-barrier
        // consumer; another wave's STAGE would race an in-flight read)
        asm volatile("s_waitcnt lgkmcnt(0)" ::: "memory");
        asm volatile("s_waitcnt vmcnt(0)" ::: "memory");
        __builtin_amdgcn_s_barrier();
        asm volatile("" ::: "memory");
    }
    // ---- epilogue: held H1 of last tile ----
    MFMA_Q(1, 1, af1, bq1);
    MFMA_Q(1, 0, af1, bq0);
#undef STAGE_A
#undef STAGE_B
#undef LOAD_AF
#undef LOAD_BQ
#undef MFMA_Q

    // ---- C write: C[row][col], row = 16*am + hi*4 + i, col = 16*an + lr ----
    #pragma unroll
    for (int m = 0; m < 8; ++m) {
        #pragma unroll
        for (int n = 0; n < 4; ++n) {
            #pragma unroll
            for (int i = 0; i < 4; ++i) {
                long row = brow + wm * 128 + m * 16 + hi * 4 + i;
                long col = bcol + wn * 64 + n * 16 + lr;
                float vv = acc[m][n][i] * alpha;
                if constexpr (sizeof(CT) == 2) {
                    ((unsigned short*)C)[row * (long)N + col] = f2bf(vv);
                } else {
                    ((float*)C)[row * (long)N + col] = vv;
                }
            }
        }
    }
}

// ---------------- bf16 transpose: dst[c][r] = src[r][c], per-batch ----------------
__global__ __launch_bounds__(256) void transpose_bf16(const unsigned short* __restrict__ src,
                                                      unsigned short* __restrict__ dst,
                                                      int srows, int scols) {
    __shared__ unsigned short tile[64][66];
    const long bofs = (long)blockIdx.z * srows * scols;
    const unsigned short* s = src + bofs;
    unsigned short* d = dst + bofs;
    const int c0 = blockIdx.x * 64;
    const int r0 = blockIdx.y * 64;
    const int tx = threadIdx.x & 15;
    const int ty = threadIdx.x >> 4;

    #pragma unroll
    for (int k = 0; k < 4; ++k) {
        int r = ty + 16 * k;
        ushort4 v = *(const ushort4*)(s + (long)(r0 + r) * scols + c0 + tx * 4);
        tile[r][tx * 4 + 0] = v.x; tile[r][tx * 4 + 1] = v.y;
        tile[r][tx * 4 + 2] = v.z; tile[r][tx * 4 + 3] = v.w;
    }
    __syncthreads();
    #pragma unroll
    for (int k = 0; k < 4; ++k) {
        int dr = ty + 16 * k;
        ushort4 v;
        v.x = tile[tx * 4 + 0][dr]; v.y = tile[tx * 4 + 1][dr];
        v.z = tile[tx * 4 + 2][dr]; v.w = tile[tx * 4 + 3][dr];
        *(ushort4*)(d + (long)(c0 + dr) * srows + r0 + tx * 4) = v;
    }
}

// ---------------- row softmax, in place, bf16, ncols = 4096 ----------------
__global__ __launch_bounds__(256) void softmax_inplace(unsigned short* __restrict__ S, int ncols) {
    const long row = blockIdx.x;
    unsigned short* p = S + row * (long)ncols;
    const int t = threadIdx.x;
    const int wid = t >> 6;

    ushort4 raw[4];
    const ushort4* pv = (const ushort4*)(p + t * 16);
    #pragma unroll
    for (int i = 0; i < 4; ++i) raw[i] = pv[i];

    float v[16];
    float mx = -1e30f;
    #pragma unroll
    for (int i = 0; i < 4; ++i) {
        v[4*i+0] = bf2f(raw[i].x); v[4*i+1] = bf2f(raw[i].y);
        v[4*i+2] = bf2f(raw[i].z); v[4*i+3] = bf2f(raw[i].w);
    }
    #pragma unroll
    for (int i = 0; i < 16; ++i) mx = fmaxf(mx, v[i]);
    #pragma unroll
    for (int off = 32; off > 0; off >>= 1) mx = fmaxf(mx, __shfl_xor(mx, off));

    __shared__ float red[8];
    if ((t & 63) == 0) red[wid] = mx;
    __syncthreads();
    mx = fmaxf(fmaxf(red[0], red[1]), fmaxf(red[2], red[3]));

    float sum = 0.f;
    #pragma unroll
    for (int i = 0; i < 16; ++i) { v[i] = __expf(v[i] - mx); sum += v[i]; }
    #pragma unroll
    for (int off = 32; off > 0; off >>= 1) sum += __shfl_xor(sum, off);
    __syncthreads();
    if ((t & 63) == 0) red[4 + wid] = sum;
    __syncthreads();
    sum = red[4] + red[5] + red[6] + red[7];
    const float inv = 1.0f / sum;

    ushort4* po = (ushort4*)(p + t * 16);
    #pragma unroll
    for (int i = 0; i < 4; ++i) {
        ushort4 o;
        o.x = f2bf(v[4*i+0] * inv); o.y = f2bf(v[4*i+1] * inv);
        o.z = f2bf(v[4*i+2] * inv); o.w = f2bf(v[4*i+3] * inv);
        po[i] = o;
    }
}

extern "C" void kernel_launch(void* const* d_in, const int* in_sizes, int n_in,
                              void* d_out, int out_size, void* d_ws, size_t ws_size,
                              hipStream_t stream) {
    const float* x  = (const float*)d_in[0];
    const float* wq = (const float*)d_in[1];
    const float* wk = (const float*)d_in[2];
    const float* wv = (const float*)d_in[3];
    const float* wo = (const float*)d_in[4];
    float* out = (float*)d_out;

    const long SDIM = 2048, SEQ = 4096, BATCH = 2;
    const long MS = BATCH * SEQ;       // 8192
    const long XN = MS * SDIM;         // 16,777,216
    const long WN = SDIM * SDIM;       // 4,194,304

    unsigned short* ws  = (unsigned short*)d_ws;
    unsigned short* Xbf = ws;               // XN elems (reused as Vt later)
    unsigned short* Wqb = ws + XN;
    unsigned short* Wkb = Wqb + WN;
    unsigned short* Wvb = Wkb + WN;
    unsigned short* Wob = Wvb + WN;
    unsigned short* Qb  = Wob + WN;         // XN (reused as Ctx later)
    unsigned short* Kb  = Qb + XN;
    unsigned short* Vb  = Kb + XN;
    unsigned short* Sb  = Vb + XN;          // 2*4096*4096 bf16
    unsigned short* Vt  = Xbf;
    unsigned short* Ctx = Qb;

    // fp32 -> bf16 conversions
    cvt_f32_bf16<<<(int)(XN / 2048), 256, 0, stream>>>(x,  Xbf, XN);
    cvt_f32_bf16<<<(int)(WN / 2048), 256, 0, stream>>>(wq, Wqb, WN);
    cvt_f32_bf16<<<(int)(WN / 2048), 256, 0, stream>>>(wk, Wkb, WN);
    cvt_f32_bf16<<<(int)(WN / 2048), 256, 0, stream>>>(wv, Wvb, WN);
    cvt_f32_bf16<<<(int)(WN / 2048), 256, 0, stream>>>(wo, Wob, WN);

    // projections: [8192,2048] = Xbf @ W^T
    dim3 gp((unsigned)(MS / 256), (unsigned)(SDIM / 256), 1);
    gemm256_bt<unsigned short><<<gp, 512, 0, stream>>>(Xbf, Wqb, Qb, (int)SDIM, (int)SDIM, (int)(SDIM / 64), 0, 0, 0, 1.0f);
    gemm256_bt<unsigned short><<<gp, 512, 0, stream>>>(Xbf, Wkb, Kb, (int)SDIM, (int)SDIM, (int)(SDIM / 64), 0, 0, 0, 1.0f);
    gemm256_bt<unsigned short><<<gp, 512, 0, stream>>>(Xbf, Wvb, Vb, (int)SDIM, (int)SDIM, (int)(SDIM / 64), 0, 0, 0, 1.0f);

    // V -> V^T per batch (Vt overwrites Xbf region; X no longer needed)
    dim3 gt((unsigned)(SDIM / 64), (unsigned)(SEQ / 64), (unsigned)BATCH);
    transpose_bf16<<<gt, 256, 0, stream>>>(Vb, Vt, (int)SEQ, (int)SDIM);

    // scores: S[b] = Q[b] @ K[b]^T * (1/sqrt(D))
    const float scale = 1.0f / sqrtf((float)SDIM);
    dim3 gs((unsigned)(SEQ / 256), (unsigned)(SEQ / 256), (unsigned)BATCH);
    gemm256_bt<unsigned short><<<gs, 512, 0, stream>>>(Qb, Kb, Sb, (int)SEQ, (int)SDIM, (int)(SDIM / 64),
                                                       SEQ * SDIM, SEQ * SDIM, SEQ * SEQ, scale);

    // softmax rows in place
    softmax_inplace<<<(int)(BATCH * SEQ), 256, 0, stream>>>(Sb, (int)SEQ);

    // ctx[b] = P[b] @ Vt[b]^T : M=SEQ, N=SDIM, K=SEQ  (Ctx overwrites Qb)
    dim3 gc((unsigned)(SEQ / 256), (unsigned)(SDIM / 256), (unsigned)BATCH);
    gemm256_bt<unsigned short><<<gc, 512, 0, stream>>>(Sb, Vt, Ctx, (int)SDIM, (int)SEQ, (int)(SEQ / 64),
                                                       SEQ * SEQ, SDIM * SEQ, SEQ * SDIM, 1.0f);

    // out = Ctx @ Wo^T  (fp32 out, flat [8192,2048])
    gemm256_bt<float><<<gp, 512, 0, stream>>>(Ctx, Wob, out, (int)SDIM, (int)SDIM, (int)(SDIM / 64), 0, 0, 0, 1.0f);
}

// Round 11
// 512.573 us; speedup vs baseline: 1.6543x; 1.0499x over previous
//
#include <hip/hip_runtime.h>
#include <hip/hip_bf16.h>
#include <stdint.h>
#include <math.h>

typedef __attribute__((ext_vector_type(4))) float f32x4;
typedef __attribute__((ext_vector_type(8))) short s16x8;

typedef const __attribute__((address_space(1))) void* gas_ptr;
typedef __attribute__((address_space(3))) void* las_ptr;

__device__ __forceinline__ float bf2f(unsigned short u) {
    union { unsigned int i; float f; } x; x.i = ((unsigned int)u) << 16; return x.f;
}
__device__ __forceinline__ unsigned short f2bf(float f) {
    union { float f; unsigned int u; } x; x.f = f;
    unsigned int r = x.u + 0x7FFFu + ((x.u >> 16) & 1u);
    return (unsigned short)(r >> 16);
}

// ---------------- fp32 -> bf16, all 5 tensors in ONE launch ----------------
// blocks 0..8191 -> x (16M elems); then 2048 blocks each for wq,wk,wv,wo.
__global__ __launch_bounds__(256) void cvt5(const float* __restrict__ x,
                                            const float* __restrict__ wq,
                                            const float* __restrict__ wk,
                                            const float* __restrict__ wv,
                                            const float* __restrict__ wo,
                                            unsigned short* __restrict__ xb,
                                            unsigned short* __restrict__ wqb,
                                            unsigned short* __restrict__ wkb,
                                            unsigned short* __restrict__ wvb,
                                            unsigned short* __restrict__ wob) {
    int b = blockIdx.x;
    const float* src; unsigned short* dst; long off;
    if (b < 8192) {
        src = x; dst = xb; off = (long)b * 2048;
    } else {
        int w = (b - 8192) >> 11;
        off = (long)((b - 8192) & 2047) * 2048;
        src = (w == 0) ? wq : (w == 1) ? wk : (w == 2) ? wv : wo;
        dst = (w == 0) ? wqb : (w == 1) ? wkb : (w == 2) ? wvb : wob;
    }
    long i = off + threadIdx.x * 8;
    f32x4 a = *(const f32x4*)(src + i);
    f32x4 c = *(const f32x4*)(src + i + 4);
    s16x8 o;
    o[0] = (short)f2bf(a[0]); o[1] = (short)f2bf(a[1]);
    o[2] = (short)f2bf(a[2]); o[3] = (short)f2bf(a[3]);
    o[4] = (short)f2bf(c[0]); o[5] = (short)f2bf(c[1]);
    o[6] = (short)f2bf(c[2]); o[7] = (short)f2bf(c[3]);
    *(s16x8*)(dst + i) = o;
}

// ============ 256x256 bf16 GEMM, cross-barrier pipeline (r10 loop) ============
// K-loop identical to round 10 (WIN: held H1 MFMA cluster issues post-barrier,
// feeding the matrix pipe during the next tile's read burst; 1 barrier/K-tile;
// T2 swizzle col ^= ((row&7)<<3) both-sides; T1 XCD swizzle on blockIdx.x).
// NEW (MODE 1): QKV merged into one dispatch -- blockIdx.z selects {Wq->Q,
// Wk->K, Wv->Vt}; z==2 uses a transposed LDS-bounce epilogue that writes
// Vt[dim][seq] directly (kills the standalone transpose kernel): acc ->
// sm.T[col][row] scatter (stride 264 keeps rows 16B-aligned, ~2-4-way bank
// aliasing, epilogue-only) -> barrier -> coalesced short8 row stores.
template <typename CT, int MODE>
__global__ __launch_bounds__(512, 2)
void gemm256_bt(const unsigned short* __restrict__ A,
                const unsigned short* __restrict__ B0,
                const unsigned short* __restrict__ B1,
                const unsigned short* __restrict__ B2,
                CT* __restrict__ C0, CT* __restrict__ C1, CT* __restrict__ C2,
                int N, int K, int nt,
                long sA, long sB, long sC, float alpha)
{
    const unsigned short* B = B0;
    CT* C = C0;
    if constexpr (MODE == 1) {
        if (blockIdx.z == 1)      { B = B1; C = C1; }
        else if (blockIdx.z == 2) { B = B2; C = C2; }
    } else {
        A += (long)blockIdx.z * sA;
        B += (long)blockIdx.z * sB;
        C += (long)blockIdx.z * sC;
    }

    __shared__ union {
        unsigned short L[2][2][2][128][64];   // 128 KiB loop buffers
        unsigned short T[256][264];           // transpose bounce (epilogue only)
    } sm;

    const int t    = threadIdx.x;
    const int lane = t & 63;
    const int wid  = t >> 6;        // 0..7
    const int wm   = wid >> 2;      // 0..1
    const int wn   = wid & 3;       // 0..3

    // T1: XCD swizzle on x (M-tiles): XCD k gets a contiguous chunk of rows.
    const int cpx = (int)gridDim.x >> 3;
    const int bx  = ((int)blockIdx.x & 7) * cpx + ((int)blockIdx.x >> 3);
    const long brow = (long)bx * 256;
    const long bcol = (long)blockIdx.y * 256;

    const int lr = lane & 15;
    const int hi = lane >> 4;            // 0..3
    const int sw = (lr & 7) << 3;        // ds_read swizzle (element units)

    // ---- staging precompute: thread t, chunk j handles linear u = t + 512j ----
    int voff[2];                      // LDS element offset u*8
    const unsigned short* pA[2][2];   // [sub][j] global src (pre-swizzled), k0=0
    const unsigned short* pB[2][2];
    {
        const unsigned short* Ab = A + brow * K;
        const unsigned short* Bb = B + bcol * K;
        #pragma unroll
        for (int j = 0; j < 2; ++j) {
            int u  = t + 512 * j;
            int ix = u >> 3;                       // phys row in [128][64] region
            int cg = u & 7;
            int cs = (cg * 8) ^ ((ix & 7) << 3);   // pre-swizzled col
            voff[j] = u * 8;
            long ra0 = ((long)(ix >> 6) << 7) | (0 << 6) | (ix & 63);
            long ra1 = ((long)(ix >> 6) << 7) | (1 << 6) | (ix & 63);
            long rb0 = ((long)(ix >> 5) << 6) | (0 << 5) | (ix & 31);
            long rb1 = ((long)(ix >> 5) << 6) | (1 << 5) | (ix & 31);
            pA[0][j] = Ab + ra0 * K + cs;
            pA[1][j] = Ab + ra1 * K + cs;
            pB[0][j] = Bb + rb0 * K + cs;
            pB[1][j] = Bb + rb1 * K + cs;
        }
    }

#define STAGE_A(H, KT) do { \
    _Pragma("unroll") \
    for (int j = 0; j < 2; ++j) \
        __builtin_amdgcn_global_load_lds((gas_ptr)(pA[H][j] + (long)(KT) * 64), \
            (las_ptr)(&sm.L[(KT) & 1][0][H][0][0] + voff[j]), 16, 0, 0); \
} while (0)
#define STAGE_B(H, KT) do { \
    _Pragma("unroll") \
    for (int j = 0; j < 2; ++j) \
        __builtin_amdgcn_global_load_lds((gas_ptr)(pB[H][j] + (long)(KT) * 64), \
            (las_ptr)(&sm.L[(KT) & 1][1][H][0][0] + voff[j]), 16, 0, 0); \
} while (0)

#define LOAD_AF(DST, CUR, QM) do { \
    _Pragma("unroll") \
    for (int m = 0; m < 4; ++m) \
        _Pragma("unroll") \
        for (int kk = 0; kk < 2; ++kk) \
            DST[m][kk] = *(const s16x8*)&sm.L[CUR][0][QM][wm * 64 + m * 16 + lr][(kk * 32 + hi * 8) ^ sw]; \
} while (0)
#define LOAD_BQ(DST, CUR, QN) do { \
    _Pragma("unroll") \
    for (int n = 0; n < 2; ++n) \
        _Pragma("unroll") \
        for (int kk = 0; kk < 2; ++kk) \
            DST[n][kk] = *(const s16x8*)&sm.L[CUR][1][QN][wn * 32 + n * 16 + lr][(kk * 32 + hi * 8) ^ sw]; \
} while (0)
#define MFMA_Q(QM, QN, AF, BQ) do { \
    _Pragma("unroll") \
    for (int m = 0; m < 4; ++m) \
        _Pragma("unroll") \
        for (int n = 0; n < 2; ++n) \
            _Pragma("unroll") \
            for (int kk = 0; kk < 2; ++kk) \
                acc[(QM) * 4 + m][(QN) * 2 + n] = __builtin_amdgcn_mfma_f32_16x16x32_bf16( \
                    AF[m][kk], BQ[n][kk], acc[(QM) * 4 + m][(QN) * 2 + n], 0, 0, 0); \
} while (0)

    f32x4 acc[8][4];
    #pragma unroll
    for (int m = 0; m < 8; ++m)
        #pragma unroll
        for (int n = 0; n < 4; ++n)
            acc[m][n] = {0.f, 0.f, 0.f, 0.f};

    s16x8 af0[4][2], af1[4][2], bq0[2][2], bq1[2][2];

    // ---- prologue: stage tile 0, drain, barrier ----
    STAGE_A(0, 0); STAGE_B(0, 0); STAGE_A(1, 0); STAGE_B(1, 0);
    asm volatile("s_waitcnt vmcnt(0)" ::: "memory");
    __builtin_amdgcn_s_barrier();
    asm volatile("" ::: "memory");

    // ---- tile 0 (no held H1 yet) ----
    LOAD_AF(af0, 0, 0);
    LOAD_BQ(bq0, 0, 0);
    LOAD_BQ(bq1, 0, 1);
    if (nt > 1) {
        STAGE_A(0, 1); STAGE_B(0, 1);
        STAGE_A(1, 1); STAGE_B(1, 1);
    }
    __builtin_amdgcn_s_setprio(1);
    MFMA_Q(0, 0, af0, bq0);
    MFMA_Q(0, 1, af0, bq1);
    __builtin_amdgcn_s_setprio(0);
    LOAD_AF(af1, 0, 1);
    asm volatile("s_waitcnt lgkmcnt(0)" ::: "memory");
    asm volatile("s_waitcnt vmcnt(0)" ::: "memory");
    __builtin_amdgcn_s_barrier();
    asm volatile("" ::: "memory");

    // ---- steady state: H1(kt-1) fills the matrix pipe during kt's read burst ----
    for (int kt = 1; kt < nt; ++kt) {
        const int cur = kt & 1;
        __builtin_amdgcn_s_setprio(1);
        MFMA_Q(1, 1, af1, bq1);
        MFMA_Q(1, 0, af1, bq0);
        __builtin_amdgcn_s_setprio(0);
        LOAD_AF(af0, cur, 0);
        LOAD_BQ(bq0, cur, 0);
        LOAD_BQ(bq1, cur, 1);
        if (kt + 1 < nt) {
            STAGE_A(0, kt + 1); STAGE_B(0, kt + 1);
            STAGE_A(1, kt + 1); STAGE_B(1, kt + 1);
        }
        __builtin_amdgcn_s_setprio(1);
        MFMA_Q(0, 0, af0, bq0);
        MFMA_Q(0, 1, af0, bq1);
        __builtin_amdgcn_s_setprio(0);
        LOAD_AF(af1, cur, 1);
        asm volatile("s_waitcnt lgkmcnt(0)" ::: "memory");
        asm volatile("s_waitcnt vmcnt(0)" ::: "memory");
        __builtin_amdgcn_s_barrier();
        asm volatile("" ::: "memory");
    }
    // ---- epilogue: held H1 of last tile ----
    MFMA_Q(1, 1, af1, bq1);
    MFMA_Q(1, 0, af1, bq0);
#undef STAGE_A
#undef STAGE_B
#undef LOAD_AF
#undef LOAD_BQ
#undef MFMA_Q

    bool transposed = false;
    if constexpr (MODE == 1) transposed = (blockIdx.z == 2);

    if (transposed) {
        // ---- V^T epilogue: acc -> sm.T[col][row] -> coalesced Vt stores ----
        __syncthreads();   // all waves done reading sm.L
        #pragma unroll
        for (int m = 0; m < 8; ++m)
            #pragma unroll
            for (int n = 0; n < 4; ++n)
                #pragma unroll
                for (int i = 0; i < 4; ++i)
                    sm.T[wn * 64 + n * 16 + lr][wm * 128 + m * 16 + hi * 4 + i] =
                        f2bf(acc[m][n][i]);
        __syncthreads();
        // Vt layout per batch: [2048 dims][4096 seq]
        const int  bz = (int)(brow >> 12);        // batch
        const long s0 = brow & 4095;              // seq offset within batch
        unsigned short* vt = (unsigned short*)C + (long)bz * 2048 * 4096;
        #pragma unroll
        for (int k = 0; k < 16; ++k) {
            int c = t + 512 * k;                  // 0..8191
            int d = c >> 5;                       // 0..255 (tile col = dim)
            int s = (c & 31) * 8;                 // 0..248 (tile row = seq)
            s16x8 v = *(const s16x8*)&sm.T[d][s];
            *(s16x8*)(vt + (bcol + d) * 4096L + s0 + s) = v;
        }
    } else {
        // ---- normal C write: row = 16*am + hi*4 + i, col = 16*an + lr ----
        #pragma unroll
        for (int m = 0; m < 8; ++m) {
            #pragma unroll
            for (int n = 0; n < 4; ++n) {
                #pragma unroll
                for (int i = 0; i < 4; ++i) {
                    long row = brow + wm * 128 + m * 16 + hi * 4 + i;
                    long col = bcol + wn * 64 + n * 16 + lr;
                    float vv = acc[m][n][i] * alpha;
                    if constexpr (sizeof(CT) == 2) {
                        ((unsigned short*)C)[row * (long)N + col] = f2bf(vv);
                    } else {
                        ((float*)C)[row * (long)N + col] = vv;
                    }
                }
            }
        }
    }
}

// ---------------- row softmax, in place, bf16, ncols = 4096 ----------------
__global__ __launch_bounds__(256) void softmax_inplace(unsigned short* __restrict__ S, int ncols) {
    const long row = blockIdx.x;
    unsigned short* p = S + row * (long)ncols;
    const int t = threadIdx.x;
    const int wid = t >> 6;

    ushort4 raw[4];
    const ushort4* pv = (const ushort4*)(p + t * 16);
    #pragma unroll
    for (int i = 0; i < 4; ++i) raw[i] = pv[i];

    float v[16];
    float mx = -1e30f;
    #pragma unroll
    for (int i = 0; i < 4; ++i) {
        v[4*i+0] = bf2f(raw[i].x); v[4*i+1] = bf2f(raw[i].y);
        v[4*i+2] = bf2f(raw[i].z); v[4*i+3] = bf2f(raw[i].w);
    }
    #pragma unroll
    for (int i = 0; i < 16; ++i) mx = fmaxf(mx, v[i]);
    #pragma unroll
    for (int off = 32; off > 0; off >>= 1) mx = fmaxf(mx, __shfl_xor(mx, off));

    __shared__ float red[8];
    if ((t & 63) == 0) red[wid] = mx;
    __syncthreads();
    mx = fmaxf(fmaxf(red[0], red[1]), fmaxf(red[2], red[3]));

    float sum = 0.f;
    #pragma unroll
    for (int i = 0; i < 16; ++i) { v[i] = __expf(v[i] - mx); sum += v[i]; }
    #pragma unroll
    for (int off = 32; off > 0; off >>= 1) sum += __shfl_xor(sum, off);
    __syncthreads();
    if ((t & 63) == 0) red[4 + wid] = sum;
    __syncthreads();
    sum = red[4] + red[5] + red[6] + red[7];
    const float inv = 1.0f / sum;

    ushort4* po = (ushort4*)(p + t * 16);
    #pragma unroll
    for (int i = 0; i < 4; ++i) {
        ushort4 o;
        o.x = f2bf(v[4*i+0] * inv); o.y = f2bf(v[4*i+1] * inv);
        o.z = f2bf(v[4*i+2] * inv); o.w = f2bf(v[4*i+3] * inv);
        po[i] = o;
    }
}

extern "C" void kernel_launch(void* const* d_in, const int* in_sizes, int n_in,
                              void* d_out, int out_size, void* d_ws, size_t ws_size,
                              hipStream_t stream) {
    const float* x  = (const float*)d_in[0];
    const float* wq = (const float*)d_in[1];
    const float* wk = (const float*)d_in[2];
    const float* wv = (const float*)d_in[3];
    const float* wo = (const float*)d_in[4];
    float* out = (float*)d_out;

    const long SDIM = 2048, SEQ = 4096, BATCH = 2;
    const long MS = BATCH * SEQ;       // 8192
    const long XN = MS * SDIM;         // 16,777,216
    const long WN = SDIM * SDIM;       // 4,194,304

    unsigned short* ws  = (unsigned short*)d_ws;
    unsigned short* Xbf = ws;
    unsigned short* Wqb = ws + XN;
    unsigned short* Wkb = Wqb + WN;
    unsigned short* Wvb = Wkb + WN;
    unsigned short* Wob = Wvb + WN;
    unsigned short* Qb  = Wob + WN;         // XN (reused as Ctx later)
    unsigned short* Kb  = Qb + XN;
    unsigned short* Vt  = Kb + XN;          // V^T, [2][2048][4096] (old Vb slot)
    unsigned short* Sb  = Vt + XN;          // 2*4096*4096 bf16
    unsigned short* Ctx = Qb;

    // fp32 -> bf16, one launch for all 5 tensors
    cvt5<<<16384, 256, 0, stream>>>(x, wq, wk, wv, wo, Xbf, Wqb, Wkb, Wvb, Wob);

    // Q,K,V^T projections in ONE dispatch (z selects weight/output; z==2
    // writes Vt via transposed epilogue)
    dim3 gqkv((unsigned)(MS / 256), (unsigned)(SDIM / 256), 3);
    gemm256_bt<unsigned short, 1><<<gqkv, 512, 0, stream>>>(
        Xbf, Wqb, Wkb, Wvb, Qb, Kb, Vt,
        (int)SDIM, (int)SDIM, (int)(SDIM / 64), 0, 0, 0, 1.0f);

    // scores: S[b] = Q[b] @ K[b]^T * (1/sqrt(D))
    const float scale = 1.0f / sqrtf((float)SDIM);
    dim3 gs((unsigned)(SEQ / 256), (unsigned)(SEQ / 256), (unsigned)BATCH);
    gemm256_bt<unsigned short, 0><<<gs, 512, 0, stream>>>(
        Qb, Kb, nullptr, nullptr, Sb, nullptr, nullptr,
        (int)SEQ, (int)SDIM, (int)(SDIM / 64),
        SEQ * SDIM, SEQ * SDIM, SEQ * SEQ, scale);

    // softmax rows in place
    softmax_inplace<<<(int)(BATCH * SEQ), 256, 0, stream>>>(Sb, (int)SEQ);

    // ctx[b] = P[b] @ Vt[b]^T : M=SEQ, N=SDIM, K=SEQ (Ctx overwrites Qb)
    dim3 gc((unsigned)(SEQ / 256), (unsigned)(SDIM / 256), (unsigned)BATCH);
    gemm256_bt<unsigned short, 0><<<gc, 512, 0, stream>>>(
        Sb, Vt, nullptr, nullptr, Ctx, nullptr, nullptr,
        (int)SDIM, (int)SEQ, (int)(SEQ / 64),
        SEQ * SEQ, SDIM * SEQ, SEQ * SDIM, 1.0f);

    // out = Ctx @ Wo^T  (fp32 out, flat [8192,2048])
    dim3 gp((unsigned)(MS / 256), (unsigned)(SDIM / 256), 1);
    gemm256_bt<float, 0><<<gp, 512, 0, stream>>>(
        Ctx, Wob, nullptr, nullptr, out, nullptr, nullptr,
        (int)SDIM, (int)SDIM, (int)(SDIM / 64), 0, 0, 0, 1.0f);
}